// Round 9
// baseline (2272.836 us; speedup 1.0000x reference)
//
#include <hip/hip_runtime.h>
#include <hip/hip_bf16.h>
#include <math.h>

namespace {
constexpr int kB = 32, kS = 1024, kT = 64, kH = 768, kNH = 12, kDH = 64;
constexpr int kNL = 32, kTopK = 64, kL = 2;
constexpr size_t kMat = (size_t)kH * kH;   // 589824
}

typedef _Float16 half8 __attribute__((ext_vector_type(8)));
typedef float floatx4 __attribute__((ext_vector_type(4)));

#define AS1U(p) ((const __attribute__((address_space(1))) unsigned int*)(p))
#define AS3U(p) ((__attribute__((address_space(3))) unsigned int*)(p))

__device__ __forceinline__ void split_write(float v, _Float16* H, _Float16* L, size_t i) {
    _Float16 h = (_Float16)v;
    H[i] = h;
    L[i] = (_Float16)(v - (float)h);
}

// ============ fused QKV MFMA GEMM (128x128 tile) -> f16 planes [fallback only] ============
template<int NP>
__global__ __launch_bounds__(256) void gemm16(
    const _Float16* __restrict__ Aqh, const _Float16* __restrict__ Aql,
    const _Float16* __restrict__ Aeh, const _Float16* __restrict__ Ael,
    const _Float16* __restrict__ Whb, const _Float16* __restrict__ Wlb,
    const float* __restrict__ bias,
    _Float16* __restrict__ O0h, _Float16* __restrict__ O0l,
    _Float16* __restrict__ O1h, _Float16* __restrict__ O1l,
    _Float16* __restrict__ O2h, _Float16* __restrict__ O2l,
    int Mq, int Mk)
{
    const int z = blockIdx.z;
    const int M = (z == 0) ? Mq : Mk;
    if ((int)blockIdx.x * 128 >= M) return;
    const _Float16* Ah = (z == 0) ? Aqh : Aeh;
    const _Float16* Al = (z == 0) ? Aql : Ael;
    const _Float16* Bh = Whb + (size_t)z * kMat;
    const _Float16* Bl = Wlb + (size_t)z * kMat;
    const float* bz = bias + z * kH;
    _Float16* Oh = (z == 0) ? O0h : (z == 1) ? O1h : O2h;
    _Float16* Ol = (z == 0) ? O0l : (z == 1) ? O1l : O2l;

    constexpr int NPL = (NP == 3) ? 4 : 2;
    __shared__ _Float16 lds[NPL * 4096];
    const int tid = threadIdx.x;
    const int lane = tid & 63, wave = tid >> 6;
    const size_t rm = (size_t)blockIdx.x * 128;
    const size_t cn = (size_t)blockIdx.y * 128;
    const int wr = (wave >> 1) * 64, wc = (wave & 1) * 64;

    const int lrow = lane >> 2;
    const int lchunk = (lane & 3) ^ ((lane >> 3) & 3);
    const int q = lane >> 4;
    const int fr = lane & 15;
    const int rslot = q ^ ((fr >> 1) & 3);

    const _Float16* gsrc;
    _Float16* lbase;
    int jbase;
    if constexpr (NP == 3) {
        gsrc = (wave == 0) ? Ah + rm * kH : (wave == 1) ? Al + rm * kH
             : (wave == 2) ? Bh + cn * kH : Bl + cn * kH;
        lbase = &lds[wave * 4096];
        jbase = 0;
    } else {
        gsrc = (wave < 2) ? Ah + rm * kH : Bh + cn * kH;
        lbase = &lds[(wave >> 1) * 4096];
        jbase = (wave & 1) * 4;
    }
    constexpr int CPW = (NP == 3) ? 8 : 4;

    floatx4 acc[4][4] = {};
    for (int k0 = 0; k0 < kH; k0 += 32) {
        #pragma unroll
        for (int c = 0; c < CPW; ++c) {
            int j = jbase + c;
            const _Float16* src = gsrc + (size_t)(j * 16 + lrow) * kH + k0 + lchunk * 8;
            _Float16* dst = lbase + j * 512 + lane * 8;
            __builtin_amdgcn_global_load_lds(AS1U(src), AS3U(dst), 16, 0, 0);
        }
        __syncthreads();
        half8 ah[4], bh[4], al[4], bl[4];
        #pragma unroll
        for (int m = 0; m < 4; ++m) {
            int r = wr + m * 16 + fr;
            ah[m] = *(const half8*)&lds[r * 32 + rslot * 8];
            if constexpr (NP == 3) al[m] = *(const half8*)&lds[4096 + r * 32 + rslot * 8];
        }
        constexpr int pb = (NP == 3) ? 2 : 1;
        #pragma unroll
        for (int n = 0; n < 4; ++n) {
            int r = wc + n * 16 + fr;
            bh[n] = *(const half8*)&lds[pb * 4096 + r * 32 + rslot * 8];
            if constexpr (NP == 3) bl[n] = *(const half8*)&lds[3 * 4096 + r * 32 + rslot * 8];
        }
        #pragma unroll
        for (int m = 0; m < 4; ++m)
            #pragma unroll
            for (int n = 0; n < 4; ++n) {
                acc[m][n] = __builtin_amdgcn_mfma_f32_16x16x32_f16(ah[m], bh[n], acc[m][n], 0, 0, 0);
                if constexpr (NP == 3) {
                    acc[m][n] = __builtin_amdgcn_mfma_f32_16x16x32_f16(ah[m], bl[n], acc[m][n], 0, 0, 0);
                    acc[m][n] = __builtin_amdgcn_mfma_f32_16x16x32_f16(al[m], bh[n], acc[m][n], 0, 0, 0);
                }
            }
        __syncthreads();
    }
    #pragma unroll
    for (int m = 0; m < 4; ++m) {
        int row0 = wr + m * 16 + (lane >> 4) * 4;
        #pragma unroll
        for (int n = 0; n < 4; ++n) {
            int col = (int)cn + wc + n * 16 + fr;
            float bv = bz[col];
            #pragma unroll
            for (int j = 0; j < 4; ++j) {
                float v = acc[m][n][j] + bv;
                size_t oi = (rm + row0 + j) * (size_t)kH + col;
                _Float16 hh = (_Float16)v;
                Oh[oi] = hh;
                if constexpr (NP == 3) Ol[oi] = (_Float16)(v - (float)hh);
            }
        }
    }
}

// ============ small-M fused QKV GEMM (64x64 tile) ============
template<int NP>
__global__ __launch_bounds__(256) void gemm16s(
    const _Float16* __restrict__ Aqh, const _Float16* __restrict__ Aql,
    const _Float16* __restrict__ Aeh, const _Float16* __restrict__ Ael,
    const _Float16* __restrict__ Whb, const _Float16* __restrict__ Wlb,
    const float* __restrict__ bias,
    _Float16* __restrict__ O0h, _Float16* __restrict__ O0l,
    _Float16* __restrict__ O1h, _Float16* __restrict__ O1l,
    _Float16* __restrict__ O2h, _Float16* __restrict__ O2l,
    int Mq, int Mk)
{
    const int z = blockIdx.z;
    const int M = (z == 0) ? Mq : Mk;
    if ((int)blockIdx.x * 64 >= M) return;
    const _Float16* Ah = (z == 0) ? Aqh : Aeh;
    const _Float16* Al = (z == 0) ? Aql : Ael;
    const _Float16* Bh = Whb + (size_t)z * kMat;
    const _Float16* Bl = Wlb + (size_t)z * kMat;
    const float* bz = bias + z * kH;
    _Float16* Oh = (z == 0) ? O0h : (z == 1) ? O1h : O2h;
    _Float16* Ol = (z == 0) ? O0l : (z == 1) ? O1l : O2l;

    constexpr int NPL = (NP == 3) ? 4 : 2;
    __shared__ _Float16 lds[NPL * 2048];
    const int tid = threadIdx.x;
    const int lane = tid & 63, wave = tid >> 6;
    const size_t rm = (size_t)blockIdx.x * 64;
    const size_t cn = (size_t)blockIdx.y * 64;
    const int wr = (wave >> 1) * 32, wc = (wave & 1) * 32;

    const int lrow = lane >> 2;
    const int lchunk = (lane & 3) ^ ((lane >> 3) & 3);
    const int q = lane >> 4;
    const int fr = lane & 15;
    const int rslot = q ^ ((fr >> 1) & 3);

    const _Float16* gsrc;
    _Float16* lbase;
    int jbase;
    if constexpr (NP == 3) {
        gsrc = (wave == 0) ? Ah + rm * kH : (wave == 1) ? Al + rm * kH
             : (wave == 2) ? Bh + cn * kH : Bl + cn * kH;
        lbase = &lds[wave * 2048];
        jbase = 0;
    } else {
        gsrc = (wave < 2) ? Ah + rm * kH : Bh + cn * kH;
        lbase = &lds[(wave >> 1) * 2048];
        jbase = (wave & 1) * 2;
    }
    constexpr int CPW = (NP == 3) ? 4 : 2;

    floatx4 acc[2][2] = {};
    for (int k0 = 0; k0 < kH; k0 += 32) {
        #pragma unroll
        for (int c = 0; c < CPW; ++c) {
            int j = jbase + c;
            const _Float16* src = gsrc + (size_t)(j * 16 + lrow) * kH + k0 + lchunk * 8;
            _Float16* dst = lbase + j * 512 + lane * 8;
            __builtin_amdgcn_global_load_lds(AS1U(src), AS3U(dst), 16, 0, 0);
        }
        __syncthreads();
        half8 ah[2], bh[2], al[2], bl[2];
        #pragma unroll
        for (int m = 0; m < 2; ++m) {
            int r = wr + m * 16 + fr;
            ah[m] = *(const half8*)&lds[r * 32 + rslot * 8];
            if constexpr (NP == 3) al[m] = *(const half8*)&lds[2048 + r * 32 + rslot * 8];
        }
        constexpr int pb = (NP == 3) ? 2 : 1;
        #pragma unroll
        for (int n = 0; n < 2; ++n) {
            int r = wc + n * 16 + fr;
            bh[n] = *(const half8*)&lds[pb * 2048 + r * 32 + rslot * 8];
            if constexpr (NP == 3) bl[n] = *(const half8*)&lds[3 * 2048 + r * 32 + rslot * 8];
        }
        #pragma unroll
        for (int m = 0; m < 2; ++m)
            #pragma unroll
            for (int n = 0; n < 2; ++n) {
                acc[m][n] = __builtin_amdgcn_mfma_f32_16x16x32_f16(ah[m], bh[n], acc[m][n], 0, 0, 0);
                if constexpr (NP == 3) {
                    acc[m][n] = __builtin_amdgcn_mfma_f32_16x16x32_f16(ah[m], bl[n], acc[m][n], 0, 0, 0);
                    acc[m][n] = __builtin_amdgcn_mfma_f32_16x16x32_f16(al[m], bh[n], acc[m][n], 0, 0, 0);
                }
            }
        __syncthreads();
    }
    #pragma unroll
    for (int m = 0; m < 2; ++m) {
        int row0 = wr + m * 16 + (lane >> 4) * 4;
        #pragma unroll
        for (int n = 0; n < 2; ++n) {
            int col = (int)cn + wc + n * 16 + fr;
            float bv = bz[col];
            #pragma unroll
            for (int j = 0; j < 4; ++j) {
                float v = acc[m][n][j] + bv;
                size_t oi = (rm + row0 + j) * (size_t)kH + col;
                _Float16 hh = (_Float16)v;
                Oh[oi] = hh;
                if constexpr (NP == 3) Ol[oi] = (_Float16)(v - (float)hh);
            }
        }
    }
}

// ============ O-projection GEMM (64x64 tile): fp32 out ============
template<int NP>
__global__ __launch_bounds__(256) void gemm_o32s(
    const _Float16* __restrict__ Ah_, const _Float16* __restrict__ Al_,
    const _Float16* __restrict__ Bh_, const _Float16* __restrict__ Bl_,
    const float* __restrict__ bias, float* __restrict__ Y, int M)
{
    constexpr int NPL = (NP == 3) ? 4 : 2;
    __shared__ _Float16 lds[NPL * 2048];
    const int tid = threadIdx.x;
    const int lane = tid & 63, wave = tid >> 6;
    const size_t rm = (size_t)blockIdx.x * 64;
    const size_t cn = (size_t)blockIdx.y * 64;
    const int wr = (wave >> 1) * 32, wc = (wave & 1) * 32;

    const int lrow = lane >> 2;
    const int lchunk = (lane & 3) ^ ((lane >> 3) & 3);
    const int q = lane >> 4;
    const int fr = lane & 15;
    const int rslot = q ^ ((fr >> 1) & 3);

    const _Float16* gsrc;
    _Float16* lbase;
    int jbase;
    if constexpr (NP == 3) {
        gsrc = (wave == 0) ? Ah_ + rm * kH : (wave == 1) ? Al_ + rm * kH
             : (wave == 2) ? Bh_ + cn * kH : Bl_ + cn * kH;
        lbase = &lds[wave * 2048];
        jbase = 0;
    } else {
        gsrc = (wave < 2) ? Ah_ + rm * kH : Bh_ + cn * kH;
        lbase = &lds[(wave >> 1) * 2048];
        jbase = (wave & 1) * 2;
    }
    constexpr int CPW = (NP == 3) ? 4 : 2;

    floatx4 acc[2][2] = {};
    for (int k0 = 0; k0 < kH; k0 += 32) {
        #pragma unroll
        for (int c = 0; c < CPW; ++c) {
            int j = jbase + c;
            const _Float16* src = gsrc + (size_t)(j * 16 + lrow) * kH + k0 + lchunk * 8;
            _Float16* dst = lbase + j * 512 + lane * 8;
            __builtin_amdgcn_global_load_lds(AS1U(src), AS3U(dst), 16, 0, 0);
        }
        __syncthreads();
        half8 ah[2], bh[2], al[2], bl[2];
        #pragma unroll
        for (int m = 0; m < 2; ++m) {
            int r = wr + m * 16 + fr;
            ah[m] = *(const half8*)&lds[r * 32 + rslot * 8];
            if constexpr (NP == 3) al[m] = *(const half8*)&lds[2048 + r * 32 + rslot * 8];
        }
        constexpr int pb = (NP == 3) ? 2 : 1;
        #pragma unroll
        for (int n = 0; n < 2; ++n) {
            int r = wc + n * 16 + fr;
            bh[n] = *(const half8*)&lds[pb * 2048 + r * 32 + rslot * 8];
            if constexpr (NP == 3) bl[n] = *(const half8*)&lds[3 * 2048 + r * 32 + rslot * 8];
        }
        #pragma unroll
        for (int m = 0; m < 2; ++m)
            #pragma unroll
            for (int n = 0; n < 2; ++n) {
                acc[m][n] = __builtin_amdgcn_mfma_f32_16x16x32_f16(ah[m], bh[n], acc[m][n], 0, 0, 0);
                if constexpr (NP == 3) {
                    acc[m][n] = __builtin_amdgcn_mfma_f32_16x16x32_f16(ah[m], bl[n], acc[m][n], 0, 0, 0);
                    acc[m][n] = __builtin_amdgcn_mfma_f32_16x16x32_f16(al[m], bh[n], acc[m][n], 0, 0, 0);
                }
            }
        __syncthreads();
    }
    #pragma unroll
    for (int m = 0; m < 2; ++m) {
        int row0 = wr + m * 16 + (lane >> 4) * 4;
        #pragma unroll
        for (int n = 0; n < 2; ++n) {
            int col = (int)cn + wc + n * 16 + fr;
            float bv = bias[col];
            #pragma unroll
            for (int j = 0; j < 4; ++j)
                Y[(rm + row0 + j) * (size_t)kH + col] = acc[m][n][j] + bv;
        }
    }
}

// ============ batched GEMM (per-b): D[b] = A[b] . B[b]^T(rows) ============
template<int NP, int KD, bool OUT16>
__global__ __launch_bounds__(256) void gemmB(
    const _Float16* __restrict__ Ah, const _Float16* __restrict__ Al,
    const _Float16* __restrict__ Bh, const _Float16* __restrict__ Bl,
    float scale, float* __restrict__ O32,
    _Float16* __restrict__ O16h, _Float16* __restrict__ O16l,
    int M, int N)
{
    const int b = blockIdx.z;
    const _Float16* Ahb = Ah + (size_t)b * M * KD;
    const _Float16* Alb = Al + (size_t)b * M * KD;
    const _Float16* Bhb = Bh + (size_t)b * N * KD;
    const _Float16* Blb = Bl + (size_t)b * N * KD;

    constexpr int NPL = (NP == 3) ? 4 : 2;
    __shared__ _Float16 lds[NPL * 4096];
    const int tid = threadIdx.x;
    const int lane = tid & 63, wave = tid >> 6;
    const size_t rm = (size_t)blockIdx.x * 128;
    const size_t cn = (size_t)blockIdx.y * 128;
    const int wr = (wave >> 1) * 64, wc = (wave & 1) * 64;

    const int lrow = lane >> 2;
    const int lchunk = (lane & 3) ^ ((lane >> 3) & 3);
    const int q = lane >> 4;
    const int fr = lane & 15;
    const int rslot = q ^ ((fr >> 1) & 3);

    const _Float16* gsrc;
    _Float16* lbase;
    int jbase;
    if constexpr (NP == 3) {
        gsrc = (wave == 0) ? Ahb + rm * KD : (wave == 1) ? Alb + rm * KD
             : (wave == 2) ? Bhb + cn * KD : Blb + cn * KD;
        lbase = &lds[wave * 4096];
        jbase = 0;
    } else {
        gsrc = (wave < 2) ? Ahb + rm * KD : Bhb + cn * KD;
        lbase = &lds[(wave >> 1) * 4096];
        jbase = (wave & 1) * 4;
    }
    constexpr int CPW = (NP == 3) ? 8 : 4;

    floatx4 acc[4][4] = {};
    for (int k0 = 0; k0 < KD; k0 += 32) {
        #pragma unroll
        for (int c = 0; c < CPW; ++c) {
            int j = jbase + c;
            const _Float16* src = gsrc + (size_t)(j * 16 + lrow) * KD + k0 + lchunk * 8;
            _Float16* dst = lbase + j * 512 + lane * 8;
            __builtin_amdgcn_global_load_lds(AS1U(src), AS3U(dst), 16, 0, 0);
        }
        __syncthreads();
        half8 ah[4], bh[4], al[4], bl[4];
        #pragma unroll
        for (int m = 0; m < 4; ++m) {
            int r = wr + m * 16 + fr;
            ah[m] = *(const half8*)&lds[r * 32 + rslot * 8];
            if constexpr (NP == 3) al[m] = *(const half8*)&lds[4096 + r * 32 + rslot * 8];
        }
        constexpr int pb = (NP == 3) ? 2 : 1;
        #pragma unroll
        for (int n = 0; n < 4; ++n) {
            int r = wc + n * 16 + fr;
            bh[n] = *(const half8*)&lds[pb * 4096 + r * 32 + rslot * 8];
            if constexpr (NP == 3) bl[n] = *(const half8*)&lds[3 * 4096 + r * 32 + rslot * 8];
        }
        #pragma unroll
        for (int m = 0; m < 4; ++m)
            #pragma unroll
            for (int n = 0; n < 4; ++n) {
                acc[m][n] = __builtin_amdgcn_mfma_f32_16x16x32_f16(ah[m], bh[n], acc[m][n], 0, 0, 0);
                if constexpr (NP == 3) {
                    acc[m][n] = __builtin_amdgcn_mfma_f32_16x16x32_f16(ah[m], bl[n], acc[m][n], 0, 0, 0);
                    acc[m][n] = __builtin_amdgcn_mfma_f32_16x16x32_f16(al[m], bh[n], acc[m][n], 0, 0, 0);
                }
            }
        __syncthreads();
    }
    const size_t ob = (size_t)b * M * N;
    #pragma unroll
    for (int m = 0; m < 4; ++m) {
        int row0 = wr + m * 16 + (lane >> 4) * 4;
        #pragma unroll
        for (int n = 0; n < 4; ++n) {
            int col = (int)cn + wc + n * 16 + fr;
            #pragma unroll
            for (int j = 0; j < 4; ++j) {
                float v = acc[m][n][j] * scale;
                size_t oi = ob + (rm + row0 + j) * (size_t)N + col;
                if constexpr (OUT16) {
                    _Float16 hh = (_Float16)v;
                    O16h[oi] = hh;
                    if constexpr (NP == 3) O16l[oi] = (_Float16)(v - (float)hh);
                } else {
                    O32[oi] = v;
                }
            }
        }
    }
}

// ============ R = Q_h . Wk_h^T (per b,h); native-layout Wk planes ============
template<int LQ, int NP>
__global__ __launch_bounds__(256) void rgemm(
    const _Float16* __restrict__ Qh, const _Float16* __restrict__ Ql,
    const _Float16* __restrict__ Wnh, const _Float16* __restrict__ Wnl,
    _Float16* __restrict__ Rh, _Float16* __restrict__ Rl)
{
    constexpr int MM = LQ / 16;
    const int tid = threadIdx.x, lane = tid & 63, wave = tid >> 6;
    const int fr = lane & 15, part = lane >> 4;
    const int bh = blockIdx.x, b = bh / kNH, h = bh % kNH;
    const int ncol = blockIdx.y * 64 + wave * 16;

    half8 qa[MM][2][2];
    #pragma unroll
    for (int m = 0; m < MM; ++m)
        #pragma unroll
        for (int c = 0; c < 2; ++c) {
            size_t ro = (size_t)(b * LQ + m * 16 + fr) * kH + h * kDH + c * 32 + part * 8;
            qa[m][c][0] = *(const half8*)&Qh[ro];
            if constexpr (NP == 3) qa[m][c][1] = *(const half8*)&Ql[ro];
        }
    floatx4 acc[MM] = {};
    #pragma unroll
    for (int c = 0; c < 2; ++c) {
        size_t ro = (size_t)(ncol + fr) * kH + h * kDH + c * 32 + part * 8;
        half8 wb = *(const half8*)&Wnh[ro];
        half8 wl;
        if constexpr (NP == 3) wl = *(const half8*)&Wnl[ro];
        #pragma unroll
        for (int m = 0; m < MM; ++m) {
            acc[m] = __builtin_amdgcn_mfma_f32_16x16x32_f16(qa[m][c][0], wb, acc[m], 0, 0, 0);
            if constexpr (NP == 3) {
                acc[m] = __builtin_amdgcn_mfma_f32_16x16x32_f16(qa[m][c][0], wl, acc[m], 0, 0, 0);
                acc[m] = __builtin_amdgcn_mfma_f32_16x16x32_f16(qa[m][c][1], wb, acc[m], 0, 0, 0);
            }
        }
    }
    #pragma unroll
    for (int m = 0; m < MM; ++m)
        #pragma unroll
        for (int j = 0; j < 4; ++j) {
            size_t oi = (size_t)(bh * LQ + m * 16 + part * 4 + j) * kH + ncol + fr;
            float v = acc[m][j];
            _Float16 hh = (_Float16)v;
            Rh[oi] = hh;
            if constexpr (NP == 3) Rl[oi] = (_Float16)(v - (float)hh);
        }
}

// ============ O_h = Z . Wv_h + bv (per b,h); transposed-weight planes ============
template<int LQ, int NP>
__global__ __launch_bounds__(256) void ogemm(
    const _Float16* __restrict__ Zh, const _Float16* __restrict__ Zl,
    const _Float16* __restrict__ WTh, const _Float16* __restrict__ WTl,
    const float* __restrict__ bv,
    _Float16* __restrict__ Oh, _Float16* __restrict__ Ol)
{
    constexpr int MM = LQ / 16;
    const int tid = threadIdx.x, lane = tid & 63, wave = tid >> 6;
    const int fr = lane & 15, part = lane >> 4;
    const int bh = blockIdx.x, b = bh / kNH, h = bh % kNH;
    const int colbase = h * kDH + wave * 16;

    floatx4 acc[MM] = {};
    for (int c = 0; c < 24; ++c) {
        size_t wo = (size_t)(colbase + fr) * kH + c * 32 + part * 8;
        half8 wb = *(const half8*)&WTh[wo];
        half8 wl;
        if constexpr (NP == 3) wl = *(const half8*)&WTl[wo];
        #pragma unroll
        for (int m = 0; m < MM; ++m) {
            size_t ro = (size_t)(bh * LQ + m * 16 + fr) * kH + c * 32 + part * 8;
            half8 ah = *(const half8*)&Zh[ro];
            acc[m] = __builtin_amdgcn_mfma_f32_16x16x32_f16(ah, wb, acc[m], 0, 0, 0);
            if constexpr (NP == 3) {
                half8 al = *(const half8*)&Zl[ro];
                acc[m] = __builtin_amdgcn_mfma_f32_16x16x32_f16(ah, wl, acc[m], 0, 0, 0);
                acc[m] = __builtin_amdgcn_mfma_f32_16x16x32_f16(al, wb, acc[m], 0, 0, 0);
            }
        }
    }
    float bias = bv[colbase + fr];
    #pragma unroll
    for (int m = 0; m < MM; ++m)
        #pragma unroll
        for (int j = 0; j < 4; ++j) {
            size_t oi = (size_t)(b * LQ + m * 16 + part * 4 + j) * kH + colbase + fr;
            float v = acc[m][j] + bias;
            _Float16 hh = (_Float16)v;
            Oh[oi] = hh;
            if constexpr (NP == 3) Ol[oi] = (_Float16)(v - (float)hh);
        }
}

// ============ per-b transpose: X [b][1024][768] -> XT [b][768][1024] ============
template<int NPLN>
__global__ __launch_bounds__(256) void xpose(const _Float16* __restrict__ Xh,
    const _Float16* __restrict__ Xl, _Float16* __restrict__ Th, _Float16* __restrict__ Tl)
{
    __shared__ _Float16 t[2][32][33];
    const int b = blockIdx.z, e0 = blockIdx.x * 32, k0 = blockIdx.y * 32;
    const int tid = threadIdx.x;
    #pragma unroll
    for (int i = 0; i < 4; ++i) {
        int idx = tid + i * 256, r = idx >> 5, c = idx & 31;
        t[0][r][c] = Xh[((size_t)b * kS + k0 + r) * kH + e0 + c];
        if constexpr (NPLN == 2) t[1][r][c] = Xl[((size_t)b * kS + k0 + r) * kH + e0 + c];
    }
    __syncthreads();
    #pragma unroll
    for (int i = 0; i < 4; ++i) {
        int idx = tid + i * 256, r = idx >> 5, c = idx & 31;
        Th[((size_t)b * kH + e0 + r) * kS + k0 + c] = t[0][c][r];
        if constexpr (NPLN == 2) Tl[((size_t)b * kH + e0 + r) * kS + k0 + c] = t[1][c][r];
    }
}

// ============ wave-per-row softmax on f32 S rows -> f16 P planes (+f32 capture) ============
template<int NP, bool CAP>
__global__ __launch_bounds__(256) void softmax_f32(float* __restrict__ S,
    _Float16* __restrict__ Ph, _Float16* __restrict__ Pl, int nrows)
{
    const int row = blockIdx.x * 4 + (threadIdx.x >> 6);
    if (row >= nrows) return;
    const int lane = threadIdx.x & 63;
    float* s = S + (size_t)row * kS;
    float v[16];
    #pragma unroll
    for (int i = 0; i < 4; ++i) {
        float4 x = *(const float4*)&s[i * 256 + lane * 4];
        v[i * 4] = x.x; v[i * 4 + 1] = x.y; v[i * 4 + 2] = x.z; v[i * 4 + 3] = x.w;
    }
    float mx = v[0];
    #pragma unroll
    for (int i = 1; i < 16; ++i) mx = fmaxf(mx, v[i]);
    #pragma unroll
    for (int o = 1; o < 64; o <<= 1) mx = fmaxf(mx, __shfl_xor(mx, o));
    float sum = 0.f;
    #pragma unroll
    for (int i = 0; i < 16; ++i) { v[i] = expf(v[i] - mx); sum += v[i]; }
    #pragma unroll
    for (int o = 1; o < 64; o <<= 1) sum += __shfl_xor(sum, o);
    float inv = 1.0f / sum;
    #pragma unroll
    for (int i = 0; i < 4; ++i)
        #pragma unroll
        for (int j = 0; j < 4; ++j) {
            int idx = i * 256 + lane * 4 + j;
            float p = v[i * 4 + j] * inv;
            if constexpr (CAP) s[idx] = p;
            _Float16 hh = (_Float16)p;
            Ph[(size_t)row * kS + idx] = hh;
            if constexpr (NP == 3) Pl[(size_t)row * kS + idx] = (_Float16)(p - (float)hh);
        }
}

// ============ wave-per-row softmax in-place on f16 rows ============
__global__ __launch_bounds__(256) void softmax_f16k(_Float16* __restrict__ S, int nrows)
{
    const int row = blockIdx.x * 4 + (threadIdx.x >> 6);
    if (row >= nrows) return;
    const int lane = threadIdx.x & 63;
    _Float16* s = S + (size_t)row * kS;
    float v[16];
    #pragma unroll
    for (int i = 0; i < 2; ++i) {
        half8 x = *(const half8*)&s[i * 512 + lane * 8];
        #pragma unroll
        for (int j = 0; j < 8; ++j) v[i * 8 + j] = (float)x[j];
    }
    float mx = v[0];
    #pragma unroll
    for (int i = 1; i < 16; ++i) mx = fmaxf(mx, v[i]);
    #pragma unroll
    for (int o = 1; o < 64; o <<= 1) mx = fmaxf(mx, __shfl_xor(mx, o));
    float sum = 0.f;
    #pragma unroll
    for (int i = 0; i < 16; ++i) { v[i] = expf(v[i] - mx); sum += v[i]; }
    #pragma unroll
    for (int o = 1; o < 64; o <<= 1) sum += __shfl_xor(sum, o);
    float inv = 1.0f / sum;
    #pragma unroll
    for (int i = 0; i < 2; ++i) {
        half8 o8;
        #pragma unroll
        for (int j = 0; j < 8; ++j) o8[j] = (_Float16)(v[i * 8 + j] * inv);
        *(half8*)&s[i * 512 + lane * 8] = o8;
    }
}

// ============ fused scores+softmax (Lk>=256) [fallback] ============
template<int NP>
__global__ __launch_bounds__(256) void attn_big(
    const _Float16* __restrict__ Qh, const _Float16* __restrict__ Ql,
    const _Float16* __restrict__ Kh, const _Float16* __restrict__ Kl,
    float* __restrict__ P, int Lq, int Lk)
{
    constexpr int NPL = (NP == 3) ? 2 : 1;
    const int tid = threadIdx.x, lane = tid & 63, wave = tid >> 6;
    const int fr = lane & 15, part = lane >> 4;
    const int bh = blockIdx.x, b = bh / kNH, h = bh % kNH;
    const int q0 = blockIdx.y * 32;
    const int key0 = wave * 256;
    __shared__ float red[32][4];

    half8 qa[2][2][NPL];
    #pragma unroll
    for (int m = 0; m < 2; ++m)
        #pragma unroll
        for (int c = 0; c < 2; ++c) {
            size_t ro = (size_t)(b * Lq + q0 + m * 16 + fr) * kH + h * kDH + c * 32 + part * 8;
            qa[m][c][0] = *(const half8*)&Qh[ro];
            if constexpr (NP == 3) qa[m][c][1] = *(const half8*)&Ql[ro];
        }
    floatx4 acc[2][16] = {};
    #pragma unroll
    for (int n = 0; n < 16; ++n)
        #pragma unroll
        for (int c = 0; c < 2; ++c) {
            size_t ro = (size_t)(b * Lk + key0 + n * 16 + fr) * kH + h * kDH + c * 32 + part * 8;
            half8 kh8 = *(const half8*)&Kh[ro];
            half8 kl8;
            if constexpr (NP == 3) kl8 = *(const half8*)&Kl[ro];
            #pragma unroll
            for (int m = 0; m < 2; ++m) {
                acc[m][n] = __builtin_amdgcn_mfma_f32_16x16x32_f16(qa[m][c][0], kh8, acc[m][n], 0, 0, 0);
                if constexpr (NP == 3) {
                    acc[m][n] = __builtin_amdgcn_mfma_f32_16x16x32_f16(qa[m][c][0], kl8, acc[m][n], 0, 0, 0);
                    acc[m][n] = __builtin_amdgcn_mfma_f32_16x16x32_f16(qa[m][c][1], kh8, acc[m][n], 0, 0, 0);
                }
            }
        }
    #pragma unroll
    for (int m = 0; m < 2; ++m)
        #pragma unroll
        for (int n = 0; n < 16; ++n)
            #pragma unroll
            for (int j = 0; j < 4; ++j) acc[m][n][j] *= 0.125f;
    #pragma unroll
    for (int m = 0; m < 2; ++m)
        #pragma unroll
        for (int j = 0; j < 4; ++j) {
            float v = acc[m][0][j];
            #pragma unroll
            for (int n = 1; n < 16; ++n) v = fmaxf(v, acc[m][n][j]);
            #pragma unroll
            for (int o = 1; o < 16; o <<= 1) v = fmaxf(v, __shfl_xor(v, o));
            red[m * 16 + part * 4 + j][wave] = v;
        }
    __syncthreads();
    float gm[2][4];
    #pragma unroll
    for (int m = 0; m < 2; ++m)
        #pragma unroll
        for (int j = 0; j < 4; ++j) {
            int r = m * 16 + part * 4 + j;
            gm[m][j] = fmaxf(fmaxf(red[r][0], red[r][1]), fmaxf(red[r][2], red[r][3]));
        }
    __syncthreads();
    #pragma unroll
    for (int m = 0; m < 2; ++m)
        #pragma unroll
        for (int j = 0; j < 4; ++j) {
            float s = 0.f;
            #pragma unroll
            for (int n = 0; n < 16; ++n) {
                float e = expf(acc[m][n][j] - gm[m][j]);
                acc[m][n][j] = e;
                s += e;
            }
            #pragma unroll
            for (int o = 1; o < 16; o <<= 1) s += __shfl_xor(s, o);
            red[m * 16 + part * 4 + j][wave] = s;
        }
    __syncthreads();
    #pragma unroll
    for (int m = 0; m < 2; ++m)
        #pragma unroll
        for (int j = 0; j < 4; ++j) {
            int r = m * 16 + part * 4 + j;
            float inv = 1.0f / (red[r][0] + red[r][1] + red[r][2] + red[r][3]);
            size_t rowbase = ((size_t)bh * Lq + q0 + m * 16 + part * 4 + j) * Lk + key0;
            #pragma unroll
            for (int n = 0; n < 16; ++n)
                P[rowbase + n * 16 + fr] = acc[m][n][j] * inv;
        }
}

// ============ MFMA PV (big Lk) [fallback] ============
template<int LQ, int NP>
__global__ __launch_bounds__((LQ / 16) * 64) void pv_mfma(
    const float* __restrict__ P,
    const _Float16* __restrict__ Vh, const _Float16* __restrict__ Vl,
    _Float16* __restrict__ Oh, _Float16* __restrict__ Ol, int Lk)
{
    constexpr int NW = LQ / 16, NT = NW * 64;
    constexpr int NPL = (NP == 3) ? 2 : 1;
    __shared__ _Float16 vT[NPL][64][72];
    const int tid = threadIdx.x, lane = tid & 63, wave = tid >> 6;
    const int fr = lane & 15, part = lane >> 4;
    const int bh = blockIdx.x, b = bh / kNH, h = bh % kNH;
    const int qbase = wave * 16;

    floatx4 acc[4] = {};
    for (int kb = 0; kb < Lk; kb += 64) {
        for (int idx = tid; idx < 64 * 8; idx += NT) {
            int r = idx >> 3, c8 = idx & 7;
            half8 v = *(const half8*)&Vh[(size_t)(b * Lk + kb + r) * kH + h * kDH + c8 * 8];
            #pragma unroll
            for (int e = 0; e < 8; ++e) vT[0][c8 * 8 + e][r] = v[e];
            if constexpr (NP == 3) {
                half8 w = *(const half8*)&Vl[(size_t)(b * Lk + kb + r) * kH + h * kDH + c8 * 8];
                #pragma unroll
                for (int e = 0; e < 8; ++e) vT[1][c8 * 8 + e][r] = w[e];
            }
        }
        __syncthreads();
        half8 pa[2][NPL];
        #pragma unroll
        for (int c = 0; c < 2; ++c) {
            const float* src = &P[((size_t)bh * LQ + qbase + fr) * Lk + kb + c * 32 + part * 8];
            float4 x = *(const float4*)src, y = *(const float4*)(src + 4);
            float vv[8] = {x.x, x.y, x.z, x.w, y.x, y.y, y.z, y.w};
            #pragma unroll
            for (int e = 0; e < 8; ++e) {
                _Float16 hh = (_Float16)vv[e];
                pa[c][0][e] = hh;
                if constexpr (NP == 3) pa[c][1][e] = (_Float16)(vv[e] - (float)hh);
            }
        }
        #pragma unroll
        for (int n = 0; n < 4; ++n)
            #pragma unroll
            for (int c = 0; c < 2; ++c) {
                half8 bh8 = *(const half8*)&vT[0][n * 16 + fr][c * 32 + part * 8];
                acc[n] = __builtin_amdgcn_mfma_f32_16x16x32_f16(pa[c][0], bh8, acc[n], 0, 0, 0);
                if constexpr (NP == 3) {
                    half8 bl8 = *(const half8*)&vT[1][n * 16 + fr][c * 32 + part * 8];
                    acc[n] = __builtin_amdgcn_mfma_f32_16x16x32_f16(pa[c][0], bl8, acc[n], 0, 0, 0);
                    acc[n] = __builtin_amdgcn_mfma_f32_16x16x32_f16(pa[c][1], bh8, acc[n], 0, 0, 0);
                }
            }
        __syncthreads();
    }
    #pragma unroll
    for (int n = 0; n < 4; ++n)
        #pragma unroll
        for (int j = 0; j < 4; ++j) {
            size_t oi = (size_t)(b * LQ + qbase + part * 4 + j) * kH + h * kDH + n * 16 + fr;
            float v = acc[n][j];
            _Float16 hh = (_Float16)v;
            Oh[oi] = hh;
            if constexpr (NP == 3) Ol[oi] = (_Float16)(v - (float)hh);
        }
}

// ============ fully-fused small attention (Lk<=64) ============
template<int LQ, int LK, int NP, bool MASKED, bool CAPTURE>
__global__ __launch_bounds__((LQ / 16) * 64) void attn_small(
    const _Float16* Qh, const _Float16* Ql,
    const _Float16* __restrict__ Kh, const _Float16* __restrict__ Kl,
    const _Float16* __restrict__ Vh, const _Float16* __restrict__ Vl,
    _Float16* Oh, _Float16* Ol,
    float* __restrict__ Pcap, const int* __restrict__ amask)
{
    constexpr int NW = LQ / 16, NT = NW * 64, NN = LK / 16, NC = LK / 32;
    constexpr int NPL = (NP == 3) ? 2 : 1;
    constexpr int PIT = LK + 8;
    __shared__ _Float16 vT[NPL][64][PIT];
    __shared__ _Float16 Pld[NW][NPL][16][PIT];
    const int tid = threadIdx.x, lane = tid & 63, wave = tid >> 6;
    const int fr = lane & 15, part = lane >> 4;
    const int bh = blockIdx.x, b = bh / kNH, h = bh % kNH;

    for (int idx = tid; idx < LK * 8; idx += NT) {
        int r = idx >> 3, c8 = idx & 7;
        half8 v = *(const half8*)&Vh[(size_t)(b * LK + r) * kH + h * kDH + c8 * 8];
        #pragma unroll
        for (int e = 0; e < 8; ++e) vT[0][c8 * 8 + e][r] = v[e];
        if constexpr (NP == 3) {
            half8 w = *(const half8*)&Vl[(size_t)(b * LK + r) * kH + h * kDH + c8 * 8];
            #pragma unroll
            for (int e = 0; e < 8; ++e) vT[1][c8 * 8 + e][r] = w[e];
        }
    }
    half8 qa[2][NPL];
    #pragma unroll
    for (int c = 0; c < 2; ++c) {
        size_t ro = (size_t)(b * LQ + wave * 16 + fr) * kH + h * kDH + c * 32 + part * 8;
        qa[c][0] = *(const half8*)&Qh[ro];
        if constexpr (NP == 3) qa[c][1] = *(const half8*)&Ql[ro];
    }
    floatx4 acc[NN] = {};
    #pragma unroll
    for (int n = 0; n < NN; ++n)
        #pragma unroll
        for (int c = 0; c < 2; ++c) {
            size_t ro = (size_t)(b * LK + n * 16 + fr) * kH + h * kDH + c * 32 + part * 8;
            half8 kh8 = *(const half8*)&Kh[ro];
            acc[n] = __builtin_amdgcn_mfma_f32_16x16x32_f16(qa[c][0], kh8, acc[n], 0, 0, 0);
            if constexpr (NP == 3) {
                half8 kl8 = *(const half8*)&Kl[ro];
                acc[n] = __builtin_amdgcn_mfma_f32_16x16x32_f16(qa[c][0], kl8, acc[n], 0, 0, 0);
                acc[n] = __builtin_amdgcn_mfma_f32_16x16x32_f16(qa[c][1], kh8, acc[n], 0, 0, 0);
            }
        }
    #pragma unroll
    for (int n = 0; n < NN; ++n) {
        float madd = 0.f;
        if constexpr (MASKED)
            madd = (1.0f - (float)amask[b * kT + n * 16 + fr]) * -1e4f;
        #pragma unroll
        for (int j = 0; j < 4; ++j) acc[n][j] = acc[n][j] * 0.125f + madd;
    }
    #pragma unroll
    for (int j = 0; j < 4; ++j) {
        float m = acc[0][j];
        #pragma unroll
        for (int n = 1; n < NN; ++n) m = fmaxf(m, acc[n][j]);
        #pragma unroll
        for (int o = 1; o < 16; o <<= 1) m = fmaxf(m, __shfl_xor(m, o));
        float s = 0.f;
        #pragma unroll
        for (int n = 0; n < NN; ++n) { float e = expf(acc[n][j] - m); acc[n][j] = e; s += e; }
        #pragma unroll
        for (int o = 1; o < 16; o <<= 1) s += __shfl_xor(s, o);
        float inv = 1.0f / s;
        #pragma unroll
        for (int n = 0; n < NN; ++n) acc[n][j] *= inv;
    }
    #pragma unroll
    for (int n = 0; n < NN; ++n)
        #pragma unroll
        for (int j = 0; j < 4; ++j) {
            float p = acc[n][j];
            if constexpr (CAPTURE)
                Pcap[((size_t)bh * LQ + wave * 16 + part * 4 + j) * LK + n * 16 + fr] = p;
            _Float16 ph = (_Float16)p;
            Pld[wave][0][part * 4 + j][n * 16 + fr] = ph;
            if constexpr (NP == 3)
                Pld[wave][1][part * 4 + j][n * 16 + fr] = (_Float16)(p - (float)ph);
        }
    __syncthreads();
    floatx4 o4[4] = {};
    #pragma unroll
    for (int n = 0; n < 4; ++n)
        #pragma unroll
        for (int c = 0; c < NC; ++c) {
            half8 ph8 = *(const half8*)&Pld[wave][0][fr][c * 32 + part * 8];
            half8 vh8 = *(const half8*)&vT[0][n * 16 + fr][c * 32 + part * 8];
            o4[n] = __builtin_amdgcn_mfma_f32_16x16x32_f16(ph8, vh8, o4[n], 0, 0, 0);
            if constexpr (NP == 3) {
                half8 pl8 = *(const half8*)&Pld[wave][1][fr][c * 32 + part * 8];
                half8 vl8 = *(const half8*)&vT[1][n * 16 + fr][c * 32 + part * 8];
                o4[n] = __builtin_amdgcn_mfma_f32_16x16x32_f16(ph8, vl8, o4[n], 0, 0, 0);
                o4[n] = __builtin_amdgcn_mfma_f32_16x16x32_f16(pl8, vh8, o4[n], 0, 0, 0);
            }
        }
    #pragma unroll
    for (int n = 0; n < 4; ++n)
        #pragma unroll
        for (int j = 0; j < 4; ++j) {
            size_t oi = (size_t)(b * LQ + wave * 16 + part * 4 + j) * kH + h * kDH + n * 16 + fr;
            float v = o4[n][j];
            _Float16 hh = (_Float16)v;
            Oh[oi] = hh;
            if constexpr (NP == 3) Ol[oi] = (_Float16)(v - (float)hh);
        }
}

// ============ weight convert: W fp32 -> transposed hi/lo f16 ============
__global__ __launch_bounds__(256) void wconv(const float* __restrict__ W,
    _Float16* __restrict__ Th, _Float16* __restrict__ Tl)
{
    __shared__ float t[32][33];
    const int mat = blockIdx.z;
    const int k0 = blockIdx.y * 32, n0 = blockIdx.x * 32;
    const int tid = threadIdx.x;
    #pragma unroll
    for (int i = 0; i < 4; ++i) {
        int e = tid + i * 256, r = e >> 5, c = e & 31;
        t[r][c] = W[(size_t)mat * kMat + (size_t)(k0 + r) * kH + n0 + c];
    }
    __syncthreads();
    #pragma unroll
    for (int i = 0; i < 4; ++i) {
        int e = tid + i * 256, r = e >> 5, c = e & 31;
        float v = t[c][r];
        split_write(v, Th, Tl, (size_t)mat * kMat + (size_t)(n0 + r) * kH + k0 + c);
    }
}

// ============ fp32 -> f16 hi/lo split ============
__global__ __launch_bounds__(256) void split2(const float* __restrict__ X,
    _Float16* __restrict__ H, _Float16* __restrict__ L, int n)
{
    int i = (blockIdx.x * 256 + threadIdx.x) * 4;
    if (i >= n) return;
    float4 v = *(const float4*)&X[i];
    split_write(v.x, H, L, i);
    split_write(v.y, H, L, i + 1);
    split_write(v.z, H, L, i + 2);
    split_write(v.w, H, L, i + 3);
}

// ---------------- LN(residual) + optional f16 planes ----------------
__global__ __launch_bounds__(256) void ln_residual(const float* __restrict__ X,
    const float* __restrict__ A, const float* __restrict__ g,
    const float* __restrict__ lb, float* __restrict__ Y,
    _Float16* __restrict__ Yh, _Float16* __restrict__ Yl)
{
    const size_t row = blockIdx.x;
    const int tid = threadIdx.x;
    __shared__ float red[4];
    float x[3];
    float sum = 0.f;
    #pragma unroll
    for (int i = 0; i < 3; ++i) {
        int c = tid + i * 256;
        x[i] = X[row * kH + c] + A[row * kH + c];
        sum += x[i];
    }
    for (int o = 32; o > 0; o >>= 1) sum += __shfl_xor(sum, o);
    if ((tid & 63) == 0) red[tid >> 6] = sum;
    __syncthreads();
    sum = red[0] + red[1] + red[2] + red[3];
    float mean = sum * (1.0f / 768.0f);
    float vs = 0.f;
    #pragma unroll
    for (int i = 0; i < 3; ++i) { float d = x[i] - mean; vs += d * d; }
    for (int o = 32; o > 0; o >>= 1) vs += __shfl_xor(vs, o);
    __syncthreads();
    if ((tid & 63) == 0) red[tid >> 6] = vs;
    __syncthreads();
    vs = red[0] + red[1] + red[2] + red[3];
    float inv = 1.0f / sqrtf(vs * (1.0f / 768.0f) + 1e-12f);
    #pragma unroll
    for (int i = 0; i < 3; ++i) {
        int c = tid + i * 256;
        float y = (x[i] - mean) * inv * g[c] + lb[c];
        Y[row * kH + c] = y;
        if (Yh) split_write(y, Yh, Yl, row * kH + c);
    }
}

// ---------------- mean over heads of P[B,NH,NL,S] -> [B,NL,S] ----------------
__global__ __launch_bounds__(256) void mean_heads(const float* __restrict__ P,
    float* __restrict__ out)
{
    const int bq = blockIdx.x;
    const int b = bq / kNL, q = bq % kNL;
    for (int s = threadIdx.x; s < kS; s += 256) {
        float acc = 0.f;
        for (int h = 0; h < kNH; ++h)
            acc += P[((size_t)(b * kNH + h) * kNL + q) * kS + s];
        out[(size_t)bq * kS + s] = acc * (1.0f / kNH);
    }
}

// ---------------- aas accumulation ----------------
__global__ __launch_bounds__(256) void aas_acc(const float* __restrict__ P,
    float* __restrict__ aas, int init)
{
    const int b = blockIdx.x;
    for (int idx = threadIdx.x; idx < kNL * kNL; idx += 256) {
        int q = idx >> 5, k = idx & 31;
        float acc = 0.f;
        for (int h = 0; h < kNH; ++h)
            acc += P[((size_t)(b * kNH + h) * 64 + q) * 64 + 32 + k];
        size_t o = (size_t)b * kNL * kNL + idx;
        if (init) aas[o] = acc; else aas[o] += acc;
    }
}

// ---------------- imp ----------------
__global__ __launch_bounds__(256) void imp_kernel(const float* __restrict__ aas,
    const float* __restrict__ score, float* __restrict__ imp)
{
    const int b = blockIdx.x;
    __shared__ float w[kNL];
    if (threadIdx.x < kNL) {
        float acc = 0.f;
        for (int q = 0; q < kNL; ++q)
            acc += aas[((size_t)b * kNL + q) * kNL + threadIdx.x];
        w[threadIdx.x] = acc;
    }
    __syncthreads();
    for (int s = threadIdx.x; s < kS; s += 256) {
        float acc = 0.f;
        for (int k = 0; k < kNL; ++k)
            acc += w[k] * score[((size_t)b * kNL + k) * kS + s];
        imp[(size_t)b * kS + s] = acc;
    }
}

// ---------------- rank-based top-64 ----------------
__global__ __launch_bounds__(256) void topk_kernel(const float* __restrict__ imp,
    int* __restrict__ selidx, int* __restrict__ unselidx)
{
    const int b = blockIdx.x;
    const int tid = threadIdx.x;
    __shared__ unsigned long long keys[kS];
    __shared__ int wsum[4];
    for (int i = tid; i < kS; i += 256) {
        unsigned u = __float_as_uint(imp[(size_t)b * kS + i]);
        u = (u & 0x80000000u) ? ~u : (u | 0x80000000u);
        keys[i] = ((unsigned long long)u << 32) | (unsigned)(kS - 1 - i);
    }
    __syncthreads();
    unsigned long long me[4];
    int r[4] = {0, 0, 0, 0};
    #pragma unroll
    for (int j = 0; j < 4; ++j) me[j] = keys[tid * 4 + j];
    for (int t = 0; t < kS; ++t) {
        unsigned long long k = keys[t];
        #pragma unroll
        for (int j = 0; j < 4; ++j) r[j] += (k > me[j]) ? 1 : 0;
    }
    int flag[4], cnt = 0;
    #pragma unroll
    for (int j = 0; j < 4; ++j) { flag[j] = (r[j] < kTopK); cnt += flag[j]; }
    const int lane = tid & 63, w = tid >> 6;
    int incl = cnt;
    for (int o = 1; o < 64; o <<= 1) {
        int t = __shfl_up(incl, o);
        if (lane >= o) incl += t;
    }
    if (lane == 63) wsum[w] = incl;
    __syncthreads();
    int wbase = 0;
    for (int i = 0; i < w; ++i) wbase += wsum[i];
    int sbase = wbase + incl - cnt;
    int ubase = tid * 4 - sbase;
    #pragma unroll
    for (int j = 0; j < 4; ++j) {
        int i = tid * 4 + j;
        if (flag[j]) selidx[b * kTopK + sbase++] = i;
        else         unselidx[b * (kS - kTopK) + ubase++] = i;
    }
}

// ---------------- gathers (+planes) ----------------
__global__ __launch_bounds__(256) void bcast_q(const float* __restrict__ qt,
    float* __restrict__ q, _Float16* __restrict__ Qh, _Float16* __restrict__ Ql)
{
    const int bn = blockIdx.x;
    const int n = bn & (kNL - 1);
    for (int c = threadIdx.x; c < kH; c += 256) {
        float v = qt[(size_t)n * kH + c];
        q[(size_t)bn * kH + c] = v;
        split_write(v, Qh, Ql, (size_t)bn * kH + c);
    }
}

__global__ __launch_bounds__(256) void concat_lat(const float* __restrict__ qa,
    const float* __restrict__ qt, float* __restrict__ lat,
    _Float16* __restrict__ Lh, _Float16* __restrict__ Ll)
{
    const int br = blockIdx.x;
    const int b = br >> 6, r = br & 63;
    const float* src = (r < kNL) ? qa + (size_t)(b * kNL + r) * kH
                                 : qt + (size_t)(b * kNL + (r - kNL)) * kH;
    for (int c = threadIdx.x; c < kH; c += 256) {
        float v = src[c];
        lat[(size_t)br * kH + c] = v;
        split_write(v, Lh, Ll, (size_t)br * kH + c);
    }
}

__global__ __launch_bounds__(256) void gather_q(const float* __restrict__ audio,
    const int* __restrict__ selidx, float* __restrict__ qm,
    _Float16* __restrict__ Qh, _Float16* __restrict__ Ql)
{
    const int bj = blockIdx.x;
    const int b = bj >> 6;
    const int srow = selidx[bj];
    const float* src = audio + ((size_t)b * kS + srow) * kH;
    for (int c = threadIdx.x; c < kH; c += 256) {
        float v = src[c];
        qm[(size_t)bj * kH + c] = v;
        split_write(v, Qh, Ql, (size_t)bj * kH + c);
    }
}

__global__ __launch_bounds__(256) void build_kv(const float* __restrict__ audio,
    const float* __restrict__ fused, const int* __restrict__ unselidx,
    _Float16* __restrict__ Kh, _Float16* __restrict__ Kl)
{
    const int br = blockIdx.x;
    const int b = br >> 10, r = br & 1023;
    const float* src;
    if (r < kS - kTopK) src = audio + ((size_t)b * kS + unselidx[b * (kS - kTopK) + r]) * kH;
    else                src = fused + (size_t)(b * kTopK + (r - (kS - kTopK))) * kH;
    for (int c = threadIdx.x; c < kH; c += 256)
        split_write(src[c], Kh, Kl, (size_t)br * kH + c);
}

extern "C" void kernel_launch(void* const* d_in, const int* in_sizes, int n_in,
                              void* d_out, int out_size, void* d_ws, size_t ws_size,
                              hipStream_t stream)
{
    const float* audio    = (const float*)d_in[0];
    const float* text     = (const float*)d_in[1];
    const int*   amask    = (const int*)  d_in[2];
    const float* audio_qt = (const float*)d_in[3];
    const float* text_qt  = (const float*)d_in[4];
    const float* tm_w  = (const float*)d_in[5];
    const float* tm_b  = (const float*)d_in[6];
    const float* tm_g  = (const float*)d_in[7];
    const float* tm_lb = (const float*)d_in[8];
    const float* am_w  = (const float*)d_in[9];
    const float* am_b  = (const float*)d_in[10];
    const float* am_g  = (const float*)d_in[11];
    const float* am_lb = (const float*)d_in[12];
    const float* mg_w  = (const float*)d_in[13];
    const float* mg_b  = (const float*)d_in[14];
    const float* mg_g  = (const float*)d_in[15];
    const float* mg_lb = (const float*)d_in[16];
    const float* sel_w  = (const float*)d_in[17];
    const float* sel_b  = (const float*)d_in[18];
    const float* sel_g  = (const float*)d_in[19];
    const float* sel_lb = (const float*)d_in[20];
    (void)in_sizes; (void)n_in; (void)out_size;

    char* base = (char*)d_ws;
    size_t off = 0;
    auto A = [&](size_t bytes) {
        off = (off + 255) & ~(size_t)255;
        void* p = base + off; off += bytes; return p;
    };

    float *Pbuf, *attA, *q_text, *q_audio, *latent, *qmerge, *latsc, *aas, *impb;
    int *selidx, *unselidx;
    _Float16 *Wh, *Wl, *WkNh, *WkNl, *BGh, *BGl, *PTh, *PTl;
    _Float16 *PLqh, *PLql, *PLoh, *PLol, *KVh, *KVl, *XTh, *XTl, *RPreg;

    auto alloc_common = [&]() {
        attA   = (float*)A((size_t)2048 * kH * 4);
        q_text = (float*)A((size_t)1024 * kH * 4);
        q_audio= (float*)A((size_t)1024 * kH * 4);
        latent = (float*)A((size_t)2048 * kH * 4);
        qmerge = (float*)A((size_t)2048 * kH * 4);
        latsc  = (float*)A((size_t)kB * kNL * kS * 4);
        aas    = (float*)A((size_t)kB * kNL * kNL * 4);
        impb   = (float*)A((size_t)kB * kS * 4);
        selidx = (int*)A((size_t)kB * kTopK * 4);
        unselidx = (int*)A((size_t)kB * (kS - kTopK) * 4);
        Wh = (_Float16*)A(8 * kMat * 2);          // per-LAYER arena (8 matrices)
        Wl = (_Float16*)A(8 * kMat * 2);
        BGh = (_Float16*)A((size_t)kB * kS * kH * 2);
        BGl = (_Float16*)A((size_t)kB * kS * kH * 2);
        PTh = (_Float16*)A((size_t)kB * kT * kH * 2);
        PTl = (_Float16*)A((size_t)kB * kT * kH * 2);
        PLqh = (_Float16*)A((size_t)2048 * kH * 2);
        PLql = (_Float16*)A((size_t)2048 * kH * 2);
        PLoh = (_Float16*)A((size_t)2048 * kH * 2);
        PLol = (_Float16*)A((size_t)2048 * kH * 2);
    };

    // ---- try factorized layout (~387 MB) ----
    off = 0;
    Pbuf = (float*)A((size_t)kB * kNH * kNL * kS * 4);       // 50.3 MB
    alloc_common();
    WkNh = (_Float16*)A(2 * kMat * 2);
    WkNl = (_Float16*)A(2 * kMat * 2);
    KVh = (_Float16*)A((size_t)2 * 2048 * kH * 2);
    KVl = (_Float16*)A((size_t)2 * 2048 * kH * 2);
    XTh = (_Float16*)A((size_t)kB * kH * kS * 2);
    XTl = (_Float16*)A((size_t)kB * kH * kS * 2);
    RPreg = (_Float16*)A((size_t)kB * 768 * kS * 2);
    bool fact = (off <= ws_size);
    if (!fact) {
        off = 0;
        Pbuf = (float*)A((size_t)kB * kNH * 64 * kS * 4);
        alloc_common();
        KVh = (_Float16*)A((size_t)kB * kS * kH * 2);
        KVl = (_Float16*)A((size_t)kB * kS * kH * 2);
        WkNh = WkNl = XTh = XTl = RPreg = nullptr;
        if (off > ws_size) return;
    }

    _Float16* Qh = PLoh;
    _Float16* Ql = PLol;

    // ---- small attention step (Lk<=64); wmat is arena-local ----
    auto attn = [&](const float* qf, int Lq,
                    const _Float16* qah, const _Float16* qal,
                    const _Float16* eah, const _Float16* eal, int Lk,
                    int wmat, const float* bias, const float* g, const float* lb,
                    const int* mask, int capture, bool np3,
                    float* q_out, _Float16* oh, _Float16* ol)
    {
        const int Mq = kB * Lq, Mk = kB * Lk;
        const _Float16* WhB = Wh + (size_t)wmat * kMat;
        const _Float16* WlB = Wl + (size_t)wmat * kMat;
        _Float16* V2h = KVh + (size_t)Mk * kH;
        _Float16* V2l = KVl + (size_t)Mk * kH;
        const int gx = (Mq > Mk ? Mq : Mk) / 64;
        dim3 g1(gx, 12, 3);
        if (np3) gemm16s<3><<<g1, 256, 0, stream>>>(qah, qal, eah, eal, WhB, WlB, bias,
                     Qh, Ql, KVh, KVl, V2h, V2l, Mq, Mk);
        else     gemm16s<1><<<g1, 256, 0, stream>>>(qah, qal, eah, eal, WhB, WlB, bias,
                     Qh, Ql, KVh, KVl, V2h, V2l, Mq, Mk);
        if (Lq == 32 && Lk == 32)
            attn_small<32, 32, 3, false, false><<<kB * kNH, 128, 0, stream>>>(
                Qh, Ql, KVh, KVl, V2h, V2l, PLoh, PLol, nullptr, nullptr);
        else if (Lq == 32 && Lk == 64)
            attn_small<32, 64, 3, true, false><<<kB * kNH, 128, 0, stream>>>(
                Qh, Ql, KVh, KVl, V2h, V2l, PLoh, PLol, nullptr, mask);
        else if (np3)
            attn_small<64, 64, 3, false, true><<<kB * kNH, 256, 0, stream>>>(
                Qh, Ql, KVh, KVl, V2h, V2l, PLoh, PLol, Pbuf, nullptr);
        else
            attn_small<64, 64, 1, false, false><<<kB * kNH, 256, 0, stream>>>(
                Qh, Ql, KVh, KVl, V2h, V2l, PLoh, PLol, nullptr, nullptr);
        if (capture == 2)      aas_acc<<<kB, 256, 0, stream>>>(Pbuf, aas, 1);
        else if (capture == 3) aas_acc<<<kB, 256, 0, stream>>>(Pbuf, aas, 0);
        dim3 g4(Mq / 64, 12);
        if (np3) gemm_o32s<3><<<g4, 256, 0, stream>>>(PLoh, PLol, WhB + 3 * kMat, WlB + 3 * kMat,
                     bias + 3 * kH, attA, Mq);
        else     gemm_o32s<1><<<g4, 256, 0, stream>>>(PLoh, PLol, WhB + 3 * kMat, WlB + 3 * kMat,
                     bias + 3 * kH, attA, Mq);
        ln_residual<<<Mq, 256, 0, stream>>>(qf, attA, g, lb, q_out, oh, ol);
    };

    // ---- big cross step, factorized ----
    auto big_fact = [&](const float* qf, int Lq,
                        const _Float16* qah, const _Float16* qal,
                        int wmat, int kl, const float* bias,
                        const float* g, const float* lb,
                        int capture, bool np3,
                        float* q_out, _Float16* oh, _Float16* ol)
    {
        const int Mq = kB * Lq;
        const int MR = kNH * Lq;
        const _Float16* WhB = Wh + (size_t)wmat * kMat;
        const _Float16* WlB = Wl + (size_t)wmat * kMat;
        dim3 gq(Mq / 64, 12, 1);
        if (np3) gemm16s<3><<<gq, 256, 0, stream>>>(qah, qal, qah, qal, WhB, WlB, bias,
                     Qh, Ql, nullptr, nullptr, nullptr, nullptr, Mq, Mq);
        else     gemm16s<1><<<gq, 256, 0, stream>>>(qah, qal, qah, qal, WhB, WlB, bias,
                     Qh, Ql, nullptr, nullptr, nullptr, nullptr, Mq, Mq);
        const _Float16* WKh = WkNh + (size_t)kl * kMat;
        const _Float16* WKl = WkNl + (size_t)kl * kMat;
        const int nrows = kB * MR;
        if (np3) {
            _Float16* Rh = RPreg;
            _Float16* Rl = RPreg + (size_t)kB * MR * kH;
            rgemm<32, 3><<<dim3(kB * kNH, 12), 256, 0, stream>>>(Qh, Ql, WKh, WKl, Rh, Rl);
            gemmB<3, 768, false><<<dim3(MR / 128, kS / 128, kB), 256, 0, stream>>>(
                Rh, Rl, BGh, BGl, 0.125f, Pbuf, nullptr, nullptr, MR, kS);
            _Float16* Ph = RPreg;
            _Float16* Pl = RPreg + (size_t)kB * MR * kS;
            if (capture == 1) softmax_f32<3, true><<<(nrows + 3) / 4, 256, 0, stream>>>(Pbuf, Ph, Pl, nrows);
            else              softmax_f32<3, false><<<(nrows + 3) / 4, 256, 0, stream>>>(Pbuf, Ph, Pl, nrows);
            if (capture == 1) mean_heads<<<kB * kNL, 256, 0, stream>>>(Pbuf, latsc);
            _Float16* Zh = (_Float16*)Pbuf;
            _Float16* Zl = Zh + (size_t)kB * MR * kH;
            gemmB<3, 1024, true><<<dim3(MR / 128, kH / 128, kB), 256, 0, stream>>>(
                Ph, Pl, XTh, XTl, 1.0f, nullptr, Zh, Zl, MR, kH);
            ogemm<32, 3><<<kB * kNH, 256, 0, stream>>>(Zh, Zl, WhB + 2 * kMat, WlB + 2 * kMat,
                bias + 2 * kH, PLoh, PLol);
        } else {
            _Float16* Rh = RPreg;
            rgemm<64, 1><<<dim3(kB * kNH, 12), 256, 0, stream>>>(Qh, Ql, WKh, WKl, Rh, Rh);
            _Float16* S16 = (_Float16*)Pbuf;
            gemmB<1, 768, true><<<dim3(MR / 128, kS / 128, kB), 256, 0, stream>>>(
                Rh, Rh, BGh, BGh, 0.125f, nullptr, S16, nullptr, MR, kS);
            softmax_f16k<<<(nrows + 3) / 4, 256, 0, stream>>>(S16, nrows);
            _Float16* Zh = RPreg;
            gemmB<1, 1024, true><<<dim3(MR / 128, kH / 128, kB), 256, 0, stream>>>(
                S16, S16, XTh, XTh, 1.0f, nullptr, Zh, nullptr, MR, kH);
            ogemm<64, 1><<<kB * kNH, 256, 0, stream>>>(Zh, Zh, WhB + 2 * kMat, WlB + 2 * kMat,
                bias + 2 * kH, PLoh, PLol);
        }
        dim3 g4(Mq / 64, 12);
        if (np3) gemm_o32s<3><<<g4, 256, 0, stream>>>(PLoh, PLol, WhB + 3 * kMat, WlB + 3 * kMat,
                     bias + 3 * kH, attA, Mq);
        else     gemm_o32s<1><<<g4, 256, 0, stream>>>(PLoh, PLol, WhB + 3 * kMat, WlB + 3 * kMat,
                     bias + 3 * kH, attA, Mq);
        ln_residual<<<Mq, 256, 0, stream>>>(qf, attA, g, lb, q_out, oh, ol);
    };

    // ---- big cross step, fallback (round-7 path) ----
    auto big_fb = [&](const float* qf, int Lq,
                      const _Float16* qah, const _Float16* qal,
                      const _Float16* eah, const _Float16* eal,
                      int wmat, const float* bias, const float* g, const float* lb,
                      int capture, bool np3,
                      float* q_out, _Float16* oh, _Float16* ol)
    {
        const int Mq = kB * Lq, Mk = kB * kS;
        const _Float16* WhB = Wh + (size_t)wmat * kMat;
        const _Float16* WlB = Wl + (size_t)wmat * kMat;
        const int gx = Mk / 128;
        dim3 g1(gx, 6, 2);
        if (np3) gemm16<3><<<g1, 256, 0, stream>>>(qah, qal, eah, eal, WhB, WlB, bias,
                     Qh, Ql, KVh, KVl, nullptr, nullptr, Mq, Mk);
        else     gemm16<1><<<g1, 256, 0, stream>>>(qah, qal, eah, eal, WhB, WlB, bias,
                     Qh, Ql, KVh, KVl, nullptr, nullptr, Mq, Mk);
        dim3 g2(kB * kNH, Lq / 32);
        if (np3) attn_big<3><<<g2, 256, 0, stream>>>(Qh, Ql, KVh, KVl, Pbuf, Lq, kS);
        else     attn_big<1><<<g2, 256, 0, stream>>>(Qh, Ql, KVh, KVl, Pbuf, Lq, kS);
        if (capture == 1) mean_heads<<<kB * kNL, 256, 0, stream>>>(Pbuf, latsc);
        dim3 g3(Mk / 128, 6, 1);
        if (np3) gemm16<3><<<g3, 256, 0, stream>>>(eah, eal, eah, eal,
                     WhB + 2 * kMat, WlB + 2 * kMat, bias + 2 * kH,
                     KVh, KVl, nullptr, nullptr, nullptr, nullptr, Mk, Mk);
        else     gemm16<1><<<g3, 256, 0, stream>>>(eah, eal, eah, eal,
                     WhB + 2 * kMat, WlB + 2 * kMat, bias + 2 * kH,
                     KVh, KVl, nullptr, nullptr, nullptr, nullptr, Mk, Mk);
        if (Lq == 32) {
            if (np3) pv_mfma<32, 3><<<kB * kNH, 128, 0, stream>>>(Pbuf, KVh, KVl, PLoh, PLol, kS);
            else     pv_mfma<32, 1><<<kB * kNH, 128, 0, stream>>>(Pbuf, KVh, KVl, PLoh, PLol, kS);
        } else {
            if (np3) pv_mfma<64, 3><<<kB * kNH, 256, 0, stream>>>(Pbuf, KVh, KVl, PLoh, PLol, kS);
            else     pv_mfma<64, 1><<<kB * kNH, 256, 0, stream>>>(Pbuf, KVh, KVl, PLoh, PLol, kS);
        }
        dim3 g4(Mq / 64, 12);
        if (np3) gemm_o32s<3><<<g4, 256, 0, stream>>>(PLoh, PLol, WhB + 3 * kMat, WlB + 3 * kMat,
                     bias + 3 * kH, attA, Mq);
        else     gemm_o32s<1><<<g4, 256, 0, stream>>>(PLoh, PLol, WhB + 3 * kMat, WlB + 3 * kMat,
                     bias + 3 * kH, attA, Mq);
        ln_residual<<<Mq, 256, 0, stream>>>(qf, attA, g, lb, q_out, oh, ol);
    };

    split2<<<(kB * kT * kH) / 1024, 256, 0, stream>>>(text, PTh, PTl, kB * kT * kH);
    split2<<<(kB * kS * kH) / 1024, 256, 0, stream>>>(audio, BGh, BGl, kB * kS * kH);
    if (fact) xpose<2><<<dim3(24, 32, 32), 256, 0, stream>>>(BGh, BGl, XTh, XTl);

    // ---- text token merger (fp16x2; per-layer weight conversion) ----
    bcast_q<<<kB * kNL, 256, 0, stream>>>(text_qt, q_text, PLqh, PLql);
    for (int l = 0; l < kL; ++l) {
        wconv<<<dim3(24, 24, 8), 256, 0, stream>>>(tm_w + (size_t)l * 8 * kMat, Wh, Wl);
        attn(q_text, kNL, PLqh, PLql, PLqh, PLql, kNL, 0,
             tm_b + (size_t)l * 8 * kH, tm_g + (size_t)l * 2 * kH, tm_lb + (size_t)l * 2 * kH,
             nullptr, 0, true, q_text, PLqh, PLql);
        attn(q_text, kNL, PLqh, PLql, PTh, PTl, kT, 4,
             tm_b + ((size_t)l * 8 + 4) * kH, tm_g + ((size_t)l * 2 + 1) * kH, tm_lb + ((size_t)l * 2 + 1) * kH,
             amask, 0, true, q_text, PLqh, PLql);
    }
    // ---- audio token merger (capture last-layer cross probs) ----
    if (fact)
        for (int l = 0; l < kL; ++l)
            split2<<<(int)(kMat / 1024), 256, 0, stream>>>(am_w + ((size_t)l * 8 + 5) * kMat,
                WkNh + (size_t)l * kMat, WkNl + (size_t)l * kMat, (int)kMat);
    bcast_q<<<kB * kNL, 256, 0, stream>>>(audio_qt, q_audio, PLqh, PLql);
    for (int l = 0; l < kL; ++l) {
        wconv<<<dim3(24, 24, 8), 256, 0, stream>>>(am_w + (size_t)l * 8 * kMat, Wh, Wl);
        attn(q_audio, kNL, PLqh, PLql, PLqh, PLql, kNL, 0,
             am_b + (size_t)l * 8 * kH, am_g + (size_t)l * 2 * kH, am_lb + (size_t)l * 2 * kH,
             nullptr, 0, true, q_audio, PLqh, PLql);
        if (fact)
            big_fact(q_audio, kNL, PLqh, PLql, 4, l,
                am_b + ((size_t)l * 8 + 4) * kH, am_g + ((size_t)l * 2 + 1) * kH, am_lb + ((size_t)l * 2 + 1) * kH,
                (l == kL - 1) ? 1 : 0, true, q_audio, PLqh, PLql);
        else
            big_fb(q_audio, kNL, PLqh, PLql, BGh, BGl, 4,
                am_b + ((size_t)l * 8 + 4) * kH, am_g + ((size_t)l * 2 + 1) * kH, am_lb + ((size_t)l * 2 + 1) * kH,
                (l == kL - 1) ? 1 : 0, true, q_audio, PLqh, PLql);
    }
    concat_lat<<<kB * 64, 256, 0, stream>>>(q_audio, q_text, latent, PLqh, PLql);
    // ---- self block over 64 latents (captures both layers) ----
    for (int l = 0; l < kL; ++l) {
        wconv<<<dim3(24, 24, 4), 256, 0, stream>>>(sel_w + (size_t)l * 4 * kMat, Wh, Wl);
        attn(latent, 64, PLqh, PLql, PLqh, PLql, 64, 0,
             sel_b + (size_t)l * 4 * kH, sel_g + (size_t)l * kH, sel_lb + (size_t)l * kH,
             nullptr, (l == 0) ? 2 : 3, true, latent, PLqh, PLql);
    }
    // ---- selection ----
    imp_kernel<<<kB, 256, 0, stream>>>(aas, latsc, impb);
    topk_kernel<<<kB, 256, 0, stream>>>(impb, selidx, unselidx);
    gather_q<<<kB * kTopK, 256, 0, stream>>>(audio, selidx, qmerge, PLqh, PLql);
    build_kv<<<kB * kS, 256, 0, stream>>>(audio, latent, unselidx, BGh, BGl);
    if (fact) xpose<1><<<dim3(24, 32, 32), 256, 0, stream>>>(BGh, BGh, XTh, XTh);
    // ---- merge block (fp16 1-pass) ----
    if (fact)
        for (int l = 0; l < kL; ++l)
            split2<<<(int)(kMat / 1024), 256, 0, stream>>>(mg_w + ((size_t)l * 8 + 5) * kMat,
                WkNh + (size_t)l * kMat, WkNl + (size_t)l * kMat, (int)kMat);
    for (int l = 0; l < kL; ++l) {
        wconv<<<dim3(24, 24, 8), 256, 0, stream>>>(mg_w + (size_t)l * 8 * kMat, Wh, Wl);
        attn(qmerge, 64, PLqh, PLql, PLqh, PLql, 64, 0,
             mg_b + (size_t)l * 8 * kH, mg_g + (size_t)l * 2 * kH, mg_lb + (size_t)l * 2 * kH,
             nullptr, 0, false, qmerge, PLqh, PLql);
        float* qo = (l == kL - 1) ? (float*)d_out : qmerge;
        _Float16* oh = (l == kL - 1) ? nullptr : PLqh;
        _Float16* ol = (l == kL - 1) ? nullptr : PLql;
        if (fact)
            big_fact(qmerge, 64, PLqh, PLql, 4, l,
                mg_b + ((size_t)l * 8 + 4) * kH, mg_g + ((size_t)l * 2 + 1) * kH, mg_lb + ((size_t)l * 2 + 1) * kH,
                0, false, qo, oh, ol);
        else
            big_fb(qmerge, 64, PLqh, PLql, BGh, BGl, 4,
                mg_b + ((size_t)l * 8 + 4) * kH, mg_g + ((size_t)l * 2 + 1) * kH, mg_lb + ((size_t)l * 2 + 1) * kH,
                0, false, qo, oh, ol);
    }
}

// Round 10
// 2088.212 us; speedup vs baseline: 1.0884x; 1.0884x over previous
//
#include <hip/hip_runtime.h>
#include <hip/hip_bf16.h>
#include <math.h>

namespace {
constexpr int kB = 32, kS = 1024, kT = 64, kH = 768, kNH = 12, kDH = 64;
constexpr int kNL = 32, kTopK = 64, kL = 2;
constexpr size_t kMat = (size_t)kH * kH;   // 589824
}

typedef _Float16 half8 __attribute__((ext_vector_type(8)));
typedef float floatx4 __attribute__((ext_vector_type(4)));

#define AS1U(p) ((const __attribute__((address_space(1))) unsigned int*)(p))
#define AS3U(p) ((__attribute__((address_space(3))) unsigned int*)(p))

__device__ __forceinline__ void split_write(float v, _Float16* H, _Float16* L, size_t i) {
    _Float16 h = (_Float16)v;
    H[i] = h;
    L[i] = (_Float16)(v - (float)h);
}

// ============ single-matrix big GEMM (128x128), 1D XCD-swizzled A-panel-major grid ============
// grid = 6*(M/128) blocks (divisible by 8). xn fastest within swz -> the 6 blocks
// sharing one A panel run consecutively on ONE XCD -> A fetched ~once from HBM.
template<int NP>
__global__ __launch_bounds__(256) void gemm16x(
    const _Float16* __restrict__ Ah_, const _Float16* __restrict__ Al_,
    const _Float16* __restrict__ Bh_, const _Float16* __restrict__ Bl_,
    const float* __restrict__ bias,
    _Float16* __restrict__ Oh, _Float16* __restrict__ Ol, int M)
{
    const int nwg = gridDim.x;
    const int bid = blockIdx.x;
    const int cpx = nwg >> 3;
    const int swz = (bid & 7) * cpx + (bid >> 3);
    const int xn = swz % 6;
    const int ym = swz / 6;
    if (ym * 128 >= M) return;

    constexpr int NPL = (NP == 3) ? 4 : 2;
    __shared__ _Float16 lds[NPL * 4096];
    const int tid = threadIdx.x;
    const int lane = tid & 63, wave = tid >> 6;
    const size_t rm = (size_t)ym * 128;
    const size_t cn = (size_t)xn * 128;
    const int wr = (wave >> 1) * 64, wc = (wave & 1) * 64;

    const int lrow = lane >> 2;
    const int lchunk = (lane & 3) ^ ((lane >> 3) & 3);
    const int q = lane >> 4;
    const int fr = lane & 15;
    const int rslot = q ^ ((fr >> 1) & 3);     // XOR swizzle -> 2-way aliasing (free)

    const _Float16* gsrc;
    _Float16* lbase;
    int jbase;
    if constexpr (NP == 3) {
        gsrc = (wave == 0) ? Ah_ + rm * kH : (wave == 1) ? Al_ + rm * kH
             : (wave == 2) ? Bh_ + cn * kH : Bl_ + cn * kH;
        lbase = &lds[wave * 4096];
        jbase = 0;
    } else {
        gsrc = (wave < 2) ? Ah_ + rm * kH : Bh_ + cn * kH;
        lbase = &lds[(wave >> 1) * 4096];
        jbase = (wave & 1) * 4;
    }
    constexpr int CPW = (NP == 3) ? 8 : 4;

    floatx4 acc[4][4] = {};
    for (int k0 = 0; k0 < kH; k0 += 32) {
        #pragma unroll
        for (int c = 0; c < CPW; ++c) {
            int j = jbase + c;
            const _Float16* src = gsrc + (size_t)(j * 16 + lrow) * kH + k0 + lchunk * 8;
            _Float16* dst = lbase + j * 512 + lane * 8;
            __builtin_amdgcn_global_load_lds(AS1U(src), AS3U(dst), 16, 0, 0);
        }
        __syncthreads();
        half8 ah[4], bh[4], al[4], bl[4];
        #pragma unroll
        for (int m = 0; m < 4; ++m) {
            int r = wr + m * 16 + fr;
            ah[m] = *(const half8*)&lds[r * 32 + rslot * 8];
            if constexpr (NP == 3) al[m] = *(const half8*)&lds[4096 + r * 32 + rslot * 8];
        }
        constexpr int pb = (NP == 3) ? 2 : 1;
        #pragma unroll
        for (int n = 0; n < 4; ++n) {
            int r = wc + n * 16 + fr;
            bh[n] = *(const half8*)&lds[pb * 4096 + r * 32 + rslot * 8];
            if constexpr (NP == 3) bl[n] = *(const half8*)&lds[3 * 4096 + r * 32 + rslot * 8];
        }
        #pragma unroll
        for (int m = 0; m < 4; ++m)
            #pragma unroll
            for (int n = 0; n < 4; ++n) {
                acc[m][n] = __builtin_amdgcn_mfma_f32_16x16x32_f16(ah[m], bh[n], acc[m][n], 0, 0, 0);
                if constexpr (NP == 3) {
                    acc[m][n] = __builtin_amdgcn_mfma_f32_16x16x32_f16(ah[m], bl[n], acc[m][n], 0, 0, 0);
                    acc[m][n] = __builtin_amdgcn_mfma_f32_16x16x32_f16(al[m], bh[n], acc[m][n], 0, 0, 0);
                }
            }
        __syncthreads();
    }
    #pragma unroll
    for (int m = 0; m < 4; ++m) {
        int row0 = wr + m * 16 + (lane >> 4) * 4;
        #pragma unroll
        for (int n = 0; n < 4; ++n) {
            int col = (int)cn + wc + n * 16 + fr;
            float bv = bias[col];
            #pragma unroll
            for (int j = 0; j < 4; ++j) {
                float v = acc[m][n][j] + bv;
                size_t oi = (rm + row0 + j) * (size_t)kH + col;
                _Float16 hh = (_Float16)v;
                Oh[oi] = hh;
                if constexpr (NP == 3) Ol[oi] = (_Float16)(v - (float)hh);
            }
        }
    }
}

// ============ small-M fused QKV GEMM (64x64 tile) ============
template<int NP>
__global__ __launch_bounds__(256) void gemm16s(
    const _Float16* __restrict__ Aqh, const _Float16* __restrict__ Aql,
    const _Float16* __restrict__ Aeh, const _Float16* __restrict__ Ael,
    const _Float16* __restrict__ Whb, const _Float16* __restrict__ Wlb,
    const float* __restrict__ bias,
    _Float16* __restrict__ O0h, _Float16* __restrict__ O0l,
    _Float16* __restrict__ O1h, _Float16* __restrict__ O1l,
    _Float16* __restrict__ O2h, _Float16* __restrict__ O2l,
    int Mq, int Mk)
{
    const int z = blockIdx.z;
    const int M = (z == 0) ? Mq : Mk;
    if ((int)blockIdx.x * 64 >= M) return;
    const _Float16* Ah = (z == 0) ? Aqh : Aeh;
    const _Float16* Al = (z == 0) ? Aql : Ael;
    const _Float16* Bh = Whb + (size_t)z * kMat;
    const _Float16* Bl = Wlb + (size_t)z * kMat;
    const float* bz = bias + z * kH;
    _Float16* Oh = (z == 0) ? O0h : (z == 1) ? O1h : O2h;
    _Float16* Ol = (z == 0) ? O0l : (z == 1) ? O1l : O2l;

    constexpr int NPL = (NP == 3) ? 4 : 2;
    __shared__ _Float16 lds[NPL * 2048];
    const int tid = threadIdx.x;
    const int lane = tid & 63, wave = tid >> 6;
    const size_t rm = (size_t)blockIdx.x * 64;
    const size_t cn = (size_t)blockIdx.y * 64;
    const int wr = (wave >> 1) * 32, wc = (wave & 1) * 32;

    const int lrow = lane >> 2;
    const int lchunk = (lane & 3) ^ ((lane >> 3) & 3);
    const int q = lane >> 4;
    const int fr = lane & 15;
    const int rslot = q ^ ((fr >> 1) & 3);

    const _Float16* gsrc;
    _Float16* lbase;
    int jbase;
    if constexpr (NP == 3) {
        gsrc = (wave == 0) ? Ah + rm * kH : (wave == 1) ? Al + rm * kH
             : (wave == 2) ? Bh + cn * kH : Bl + cn * kH;
        lbase = &lds[wave * 2048];
        jbase = 0;
    } else {
        gsrc = (wave < 2) ? Ah + rm * kH : Bh + cn * kH;
        lbase = &lds[(wave >> 1) * 2048];
        jbase = (wave & 1) * 2;
    }
    constexpr int CPW = (NP == 3) ? 4 : 2;

    floatx4 acc[2][2] = {};
    for (int k0 = 0; k0 < kH; k0 += 32) {
        #pragma unroll
        for (int c = 0; c < CPW; ++c) {
            int j = jbase + c;
            const _Float16* src = gsrc + (size_t)(j * 16 + lrow) * kH + k0 + lchunk * 8;
            _Float16* dst = lbase + j * 512 + lane * 8;
            __builtin_amdgcn_global_load_lds(AS1U(src), AS3U(dst), 16, 0, 0);
        }
        __syncthreads();
        half8 ah[2], bh[2], al[2], bl[2];
        #pragma unroll
        for (int m = 0; m < 2; ++m) {
            int r = wr + m * 16 + fr;
            ah[m] = *(const half8*)&lds[r * 32 + rslot * 8];
            if constexpr (NP == 3) al[m] = *(const half8*)&lds[2048 + r * 32 + rslot * 8];
        }
        constexpr int pb = (NP == 3) ? 2 : 1;
        #pragma unroll
        for (int n = 0; n < 2; ++n) {
            int r = wc + n * 16 + fr;
            bh[n] = *(const half8*)&lds[pb * 2048 + r * 32 + rslot * 8];
            if constexpr (NP == 3) bl[n] = *(const half8*)&lds[3 * 2048 + r * 32 + rslot * 8];
        }
        #pragma unroll
        for (int m = 0; m < 2; ++m)
            #pragma unroll
            for (int n = 0; n < 2; ++n) {
                acc[m][n] = __builtin_amdgcn_mfma_f32_16x16x32_f16(ah[m], bh[n], acc[m][n], 0, 0, 0);
                if constexpr (NP == 3) {
                    acc[m][n] = __builtin_amdgcn_mfma_f32_16x16x32_f16(ah[m], bl[n], acc[m][n], 0, 0, 0);
                    acc[m][n] = __builtin_amdgcn_mfma_f32_16x16x32_f16(al[m], bh[n], acc[m][n], 0, 0, 0);
                }
            }
        __syncthreads();
    }
    #pragma unroll
    for (int m = 0; m < 2; ++m) {
        int row0 = wr + m * 16 + (lane >> 4) * 4;
        #pragma unroll
        for (int n = 0; n < 2; ++n) {
            int col = (int)cn + wc + n * 16 + fr;
            float bv = bz[col];
            #pragma unroll
            for (int j = 0; j < 4; ++j) {
                float v = acc[m][n][j] + bv;
                size_t oi = (rm + row0 + j) * (size_t)kH + col;
                _Float16 hh = (_Float16)v;
                Oh[oi] = hh;
                if constexpr (NP == 3) Ol[oi] = (_Float16)(v - (float)hh);
            }
        }
    }
}

// ============ O-projection GEMM (64x64 tile): fp32 out ============
template<int NP>
__global__ __launch_bounds__(256) void gemm_o32s(
    const _Float16* __restrict__ Ah_, const _Float16* __restrict__ Al_,
    const _Float16* __restrict__ Bh_, const _Float16* __restrict__ Bl_,
    const float* __restrict__ bias, float* __restrict__ Y, int M)
{
    constexpr int NPL = (NP == 3) ? 4 : 2;
    __shared__ _Float16 lds[NPL * 2048];
    const int tid = threadIdx.x;
    const int lane = tid & 63, wave = tid >> 6;
    const size_t rm = (size_t)blockIdx.x * 64;
    const size_t cn = (size_t)blockIdx.y * 64;
    const int wr = (wave >> 1) * 32, wc = (wave & 1) * 32;

    const int lrow = lane >> 2;
    const int lchunk = (lane & 3) ^ ((lane >> 3) & 3);
    const int q = lane >> 4;
    const int fr = lane & 15;
    const int rslot = q ^ ((fr >> 1) & 3);

    const _Float16* gsrc;
    _Float16* lbase;
    int jbase;
    if constexpr (NP == 3) {
        gsrc = (wave == 0) ? Ah_ + rm * kH : (wave == 1) ? Al_ + rm * kH
             : (wave == 2) ? Bh_ + cn * kH : Bl_ + cn * kH;
        lbase = &lds[wave * 2048];
        jbase = 0;
    } else {
        gsrc = (wave < 2) ? Ah_ + rm * kH : Bh_ + cn * kH;
        lbase = &lds[(wave >> 1) * 2048];
        jbase = (wave & 1) * 2;
    }
    constexpr int CPW = (NP == 3) ? 4 : 2;

    floatx4 acc[2][2] = {};
    for (int k0 = 0; k0 < kH; k0 += 32) {
        #pragma unroll
        for (int c = 0; c < CPW; ++c) {
            int j = jbase + c;
            const _Float16* src = gsrc + (size_t)(j * 16 + lrow) * kH + k0 + lchunk * 8;
            _Float16* dst = lbase + j * 512 + lane * 8;
            __builtin_amdgcn_global_load_lds(AS1U(src), AS3U(dst), 16, 0, 0);
        }
        __syncthreads();
        half8 ah[2], bh[2], al[2], bl[2];
        #pragma unroll
        for (int m = 0; m < 2; ++m) {
            int r = wr + m * 16 + fr;
            ah[m] = *(const half8*)&lds[r * 32 + rslot * 8];
            if constexpr (NP == 3) al[m] = *(const half8*)&lds[2048 + r * 32 + rslot * 8];
        }
        constexpr int pb = (NP == 3) ? 2 : 1;
        #pragma unroll
        for (int n = 0; n < 2; ++n) {
            int r = wc + n * 16 + fr;
            bh[n] = *(const half8*)&lds[pb * 2048 + r * 32 + rslot * 8];
            if constexpr (NP == 3) bl[n] = *(const half8*)&lds[3 * 2048 + r * 32 + rslot * 8];
        }
        #pragma unroll
        for (int m = 0; m < 2; ++m)
            #pragma unroll
            for (int n = 0; n < 2; ++n) {
                acc[m][n] = __builtin_amdgcn_mfma_f32_16x16x32_f16(ah[m], bh[n], acc[m][n], 0, 0, 0);
                if constexpr (NP == 3) {
                    acc[m][n] = __builtin_amdgcn_mfma_f32_16x16x32_f16(ah[m], bl[n], acc[m][n], 0, 0, 0);
                    acc[m][n] = __builtin_amdgcn_mfma_f32_16x16x32_f16(al[m], bh[n], acc[m][n], 0, 0, 0);
                }
            }
        __syncthreads();
    }
    #pragma unroll
    for (int m = 0; m < 2; ++m) {
        int row0 = wr + m * 16 + (lane >> 4) * 4;
        #pragma unroll
        for (int n = 0; n < 2; ++n) {
            int col = (int)cn + wc + n * 16 + fr;
            float bv = bias[col];
            #pragma unroll
            for (int j = 0; j < 4; ++j)
                Y[(rm + row0 + j) * (size_t)kH + col] = acc[m][n][j] + bv;
        }
    }
}

// ============ fused scores+softmax for Lk>=256: P = softmax(QK^T/8) ============
template<int NP>
__global__ __launch_bounds__(256) void attn_big(
    const _Float16* __restrict__ Qh, const _Float16* __restrict__ Ql,
    const _Float16* __restrict__ Kh, const _Float16* __restrict__ Kl,
    float* __restrict__ P, int Lq, int Lk)
{
    constexpr int NPL = (NP == 3) ? 2 : 1;
    const int tid = threadIdx.x, lane = tid & 63, wave = tid >> 6;
    const int fr = lane & 15, part = lane >> 4;
    const int bh = blockIdx.x, b = bh / kNH, h = bh % kNH;
    const int q0 = blockIdx.y * 32;
    const int key0 = wave * 256;
    __shared__ float red[32][4];

    half8 qa[2][2][NPL];
    #pragma unroll
    for (int m = 0; m < 2; ++m)
        #pragma unroll
        for (int c = 0; c < 2; ++c) {
            size_t ro = (size_t)(b * Lq + q0 + m * 16 + fr) * kH + h * kDH + c * 32 + part * 8;
            qa[m][c][0] = *(const half8*)&Qh[ro];
            if constexpr (NP == 3) qa[m][c][1] = *(const half8*)&Ql[ro];
        }
    floatx4 acc[2][16] = {};
    #pragma unroll
    for (int n = 0; n < 16; ++n)
        #pragma unroll
        for (int c = 0; c < 2; ++c) {
            size_t ro = (size_t)(b * Lk + key0 + n * 16 + fr) * kH + h * kDH + c * 32 + part * 8;
            half8 kh8 = *(const half8*)&Kh[ro];
            half8 kl8;
            if constexpr (NP == 3) kl8 = *(const half8*)&Kl[ro];
            #pragma unroll
            for (int m = 0; m < 2; ++m) {
                acc[m][n] = __builtin_amdgcn_mfma_f32_16x16x32_f16(qa[m][c][0], kh8, acc[m][n], 0, 0, 0);
                if constexpr (NP == 3) {
                    acc[m][n] = __builtin_amdgcn_mfma_f32_16x16x32_f16(qa[m][c][0], kl8, acc[m][n], 0, 0, 0);
                    acc[m][n] = __builtin_amdgcn_mfma_f32_16x16x32_f16(qa[m][c][1], kh8, acc[m][n], 0, 0, 0);
                }
            }
        }
    #pragma unroll
    for (int m = 0; m < 2; ++m)
        #pragma unroll
        for (int n = 0; n < 16; ++n)
            #pragma unroll
            for (int j = 0; j < 4; ++j) acc[m][n][j] *= 0.125f;
    #pragma unroll
    for (int m = 0; m < 2; ++m)
        #pragma unroll
        for (int j = 0; j < 4; ++j) {
            float v = acc[m][0][j];
            #pragma unroll
            for (int n = 1; n < 16; ++n) v = fmaxf(v, acc[m][n][j]);
            #pragma unroll
            for (int o = 1; o < 16; o <<= 1) v = fmaxf(v, __shfl_xor(v, o));
            red[m * 16 + part * 4 + j][wave] = v;
        }
    __syncthreads();
    float gm[2][4];
    #pragma unroll
    for (int m = 0; m < 2; ++m)
        #pragma unroll
        for (int j = 0; j < 4; ++j) {
            int r = m * 16 + part * 4 + j;
            gm[m][j] = fmaxf(fmaxf(red[r][0], red[r][1]), fmaxf(red[r][2], red[r][3]));
        }
    __syncthreads();
    #pragma unroll
    for (int m = 0; m < 2; ++m)
        #pragma unroll
        for (int j = 0; j < 4; ++j) {
            float s = 0.f;
            #pragma unroll
            for (int n = 0; n < 16; ++n) {
                float e = expf(acc[m][n][j] - gm[m][j]);
                acc[m][n][j] = e;
                s += e;
            }
            #pragma unroll
            for (int o = 1; o < 16; o <<= 1) s += __shfl_xor(s, o);
            red[m * 16 + part * 4 + j][wave] = s;
        }
    __syncthreads();
    #pragma unroll
    for (int m = 0; m < 2; ++m)
        #pragma unroll
        for (int j = 0; j < 4; ++j) {
            int r = m * 16 + part * 4 + j;
            float inv = 1.0f / (red[r][0] + red[r][1] + red[r][2] + red[r][3]);
            size_t rowbase = ((size_t)bh * Lq + q0 + m * 16 + part * 4 + j) * Lk + key0;
            #pragma unroll
            for (int n = 0; n < 16; ++n)
                P[rowbase + n * 16 + fr] = acc[m][n][j] * inv;
        }
}

// ============ MFMA PV (big Lk): O = P.V -> f16 planes ============
template<int LQ, int NP>
__global__ __launch_bounds__((LQ / 16) * 64) void pv_mfma(
    const float* __restrict__ P,
    const _Float16* __restrict__ Vh, const _Float16* __restrict__ Vl,
    _Float16* __restrict__ Oh, _Float16* __restrict__ Ol, int Lk)
{
    constexpr int NW = LQ / 16, NT = NW * 64;
    constexpr int NPL = (NP == 3) ? 2 : 1;
    __shared__ _Float16 vT[NPL][64][72];
    const int tid = threadIdx.x, lane = tid & 63, wave = tid >> 6;
    const int fr = lane & 15, part = lane >> 4;
    const int bh = blockIdx.x, b = bh / kNH, h = bh % kNH;
    const int qbase = wave * 16;

    floatx4 acc[4] = {};
    for (int kb = 0; kb < Lk; kb += 64) {
        for (int idx = tid; idx < 64 * 8; idx += NT) {
            int r = idx >> 3, c8 = idx & 7;
            half8 v = *(const half8*)&Vh[(size_t)(b * Lk + kb + r) * kH + h * kDH + c8 * 8];
            #pragma unroll
            for (int e = 0; e < 8; ++e) vT[0][c8 * 8 + e][r] = v[e];
            if constexpr (NP == 3) {
                half8 w = *(const half8*)&Vl[(size_t)(b * Lk + kb + r) * kH + h * kDH + c8 * 8];
                #pragma unroll
                for (int e = 0; e < 8; ++e) vT[1][c8 * 8 + e][r] = w[e];
            }
        }
        __syncthreads();
        half8 pa[2][NPL];
        #pragma unroll
        for (int c = 0; c < 2; ++c) {
            const float* src = &P[((size_t)bh * LQ + qbase + fr) * Lk + kb + c * 32 + part * 8];
            float4 x = *(const float4*)src, y = *(const float4*)(src + 4);
            float vv[8] = {x.x, x.y, x.z, x.w, y.x, y.y, y.z, y.w};
            #pragma unroll
            for (int e = 0; e < 8; ++e) {
                _Float16 hh = (_Float16)vv[e];
                pa[c][0][e] = hh;
                if constexpr (NP == 3) pa[c][1][e] = (_Float16)(vv[e] - (float)hh);
            }
        }
        #pragma unroll
        for (int n = 0; n < 4; ++n)
            #pragma unroll
            for (int c = 0; c < 2; ++c) {
                half8 bh8 = *(const half8*)&vT[0][n * 16 + fr][c * 32 + part * 8];
                acc[n] = __builtin_amdgcn_mfma_f32_16x16x32_f16(pa[c][0], bh8, acc[n], 0, 0, 0);
                if constexpr (NP == 3) {
                    half8 bl8 = *(const half8*)&vT[1][n * 16 + fr][c * 32 + part * 8];
                    acc[n] = __builtin_amdgcn_mfma_f32_16x16x32_f16(pa[c][0], bl8, acc[n], 0, 0, 0);
                    acc[n] = __builtin_amdgcn_mfma_f32_16x16x32_f16(pa[c][1], bh8, acc[n], 0, 0, 0);
                }
            }
        __syncthreads();
    }
    #pragma unroll
    for (int n = 0; n < 4; ++n)
        #pragma unroll
        for (int j = 0; j < 4; ++j) {
            size_t oi = (size_t)(b * LQ + qbase + part * 4 + j) * kH + h * kDH + n * 16 + fr;
            float v = acc[n][j];
            _Float16 hh = (_Float16)v;
            Oh[oi] = hh;
            if constexpr (NP == 3) Ol[oi] = (_Float16)(v - (float)hh);
        }
}

// ============ fully-fused small attention (Lk<=64) ============
template<int LQ, int LK, int NP, bool MASKED, bool CAPTURE>
__global__ __launch_bounds__((LQ / 16) * 64) void attn_small(
    const _Float16* Qh, const _Float16* Ql,
    const _Float16* __restrict__ Kh, const _Float16* __restrict__ Kl,
    const _Float16* __restrict__ Vh, const _Float16* __restrict__ Vl,
    _Float16* Oh, _Float16* Ol,
    float* __restrict__ Pcap, const int* __restrict__ amask)
{
    constexpr int NW = LQ / 16, NT = NW * 64, NN = LK / 16, NC = LK / 32;
    constexpr int NPL = (NP == 3) ? 2 : 1;
    constexpr int PIT = LK + 8;
    __shared__ _Float16 vT[NPL][64][PIT];
    __shared__ _Float16 Pld[NW][NPL][16][PIT];
    const int tid = threadIdx.x, lane = tid & 63, wave = tid >> 6;
    const int fr = lane & 15, part = lane >> 4;
    const int bh = blockIdx.x, b = bh / kNH, h = bh % kNH;

    for (int idx = tid; idx < LK * 8; idx += NT) {
        int r = idx >> 3, c8 = idx & 7;
        half8 v = *(const half8*)&Vh[(size_t)(b * LK + r) * kH + h * kDH + c8 * 8];
        #pragma unroll
        for (int e = 0; e < 8; ++e) vT[0][c8 * 8 + e][r] = v[e];
        if constexpr (NP == 3) {
            half8 w = *(const half8*)&Vl[(size_t)(b * LK + r) * kH + h * kDH + c8 * 8];
            #pragma unroll
            for (int e = 0; e < 8; ++e) vT[1][c8 * 8 + e][r] = w[e];
        }
    }
    half8 qa[2][NPL];
    #pragma unroll
    for (int c = 0; c < 2; ++c) {
        size_t ro = (size_t)(b * LQ + wave * 16 + fr) * kH + h * kDH + c * 32 + part * 8;
        qa[c][0] = *(const half8*)&Qh[ro];
        if constexpr (NP == 3) qa[c][1] = *(const half8*)&Ql[ro];
    }
    floatx4 acc[NN] = {};
    #pragma unroll
    for (int n = 0; n < NN; ++n)
        #pragma unroll
        for (int c = 0; c < 2; ++c) {
            size_t ro = (size_t)(b * LK + n * 16 + fr) * kH + h * kDH + c * 32 + part * 8;
            half8 kh8 = *(const half8*)&Kh[ro];
            acc[n] = __builtin_amdgcn_mfma_f32_16x16x32_f16(qa[c][0], kh8, acc[n], 0, 0, 0);
            if constexpr (NP == 3) {
                half8 kl8 = *(const half8*)&Kl[ro];
                acc[n] = __builtin_amdgcn_mfma_f32_16x16x32_f16(qa[c][0], kl8, acc[n], 0, 0, 0);
                acc[n] = __builtin_amdgcn_mfma_f32_16x16x32_f16(qa[c][1], kh8, acc[n], 0, 0, 0);
            }
        }
    #pragma unroll
    for (int n = 0; n < NN; ++n) {
        float madd = 0.f;
        if constexpr (MASKED)
            madd = (1.0f - (float)amask[b * kT + n * 16 + fr]) * -1e4f;
        #pragma unroll
        for (int j = 0; j < 4; ++j) acc[n][j] = acc[n][j] * 0.125f + madd;
    }
    #pragma unroll
    for (int j = 0; j < 4; ++j) {
        float m = acc[0][j];
        #pragma unroll
        for (int n = 1; n < NN; ++n) m = fmaxf(m, acc[n][j]);
        #pragma unroll
        for (int o = 1; o < 16; o <<= 1) m = fmaxf(m, __shfl_xor(m, o));
        float s = 0.f;
        #pragma unroll
        for (int n = 0; n < NN; ++n) { float e = expf(acc[n][j] - m); acc[n][j] = e; s += e; }
        #pragma unroll
        for (int o = 1; o < 16; o <<= 1) s += __shfl_xor(s, o);
        float inv = 1.0f / s;
        #pragma unroll
        for (int n = 0; n < NN; ++n) acc[n][j] *= inv;
    }
    #pragma unroll
    for (int n = 0; n < NN; ++n)
        #pragma unroll
        for (int j = 0; j < 4; ++j) {
            float p = acc[n][j];
            if constexpr (CAPTURE)
                Pcap[((size_t)bh * LQ + wave * 16 + part * 4 + j) * LK + n * 16 + fr] = p;
            _Float16 ph = (_Float16)p;
            Pld[wave][0][part * 4 + j][n * 16 + fr] = ph;
            if constexpr (NP == 3)
                Pld[wave][1][part * 4 + j][n * 16 + fr] = (_Float16)(p - (float)ph);
        }
    __syncthreads();
    floatx4 o4[4] = {};
    #pragma unroll
    for (int n = 0; n < 4; ++n)
        #pragma unroll
        for (int c = 0; c < NC; ++c) {
            half8 ph8 = *(const half8*)&Pld[wave][0][fr][c * 32 + part * 8];
            half8 vh8 = *(const half8*)&vT[0][n * 16 + fr][c * 32 + part * 8];
            o4[n] = __builtin_amdgcn_mfma_f32_16x16x32_f16(ph8, vh8, o4[n], 0, 0, 0);
            if constexpr (NP == 3) {
                half8 pl8 = *(const half8*)&Pld[wave][1][fr][c * 32 + part * 8];
                half8 vl8 = *(const half8*)&vT[1][n * 16 + fr][c * 32 + part * 8];
                o4[n] = __builtin_amdgcn_mfma_f32_16x16x32_f16(ph8, vl8, o4[n], 0, 0, 0);
                o4[n] = __builtin_amdgcn_mfma_f32_16x16x32_f16(pl8, vh8, o4[n], 0, 0, 0);
            }
        }
    #pragma unroll
    for (int n = 0; n < 4; ++n)
        #pragma unroll
        for (int j = 0; j < 4; ++j) {
            size_t oi = (size_t)(b * LQ + wave * 16 + part * 4 + j) * kH + h * kDH + n * 16 + fr;
            float v = o4[n][j];
            _Float16 hh = (_Float16)v;
            Oh[oi] = hh;
            if constexpr (NP == 3) Ol[oi] = (_Float16)(v - (float)hh);
        }
}

// ============ weight convert: W fp32 -> transposed hi/lo f16 ============
__global__ __launch_bounds__(256) void wconv(const float* __restrict__ W,
    _Float16* __restrict__ Th, _Float16* __restrict__ Tl)
{
    __shared__ float t[32][33];
    const int mat = blockIdx.z;
    const int k0 = blockIdx.y * 32, n0 = blockIdx.x * 32;
    const int tid = threadIdx.x;
    #pragma unroll
    for (int i = 0; i < 4; ++i) {
        int e = tid + i * 256, r = e >> 5, c = e & 31;
        t[r][c] = W[(size_t)mat * kMat + (size_t)(k0 + r) * kH + n0 + c];
    }
    __syncthreads();
    #pragma unroll
    for (int i = 0; i < 4; ++i) {
        int e = tid + i * 256, r = e >> 5, c = e & 31;
        float v = t[c][r];
        split_write(v, Th, Tl, (size_t)mat * kMat + (size_t)(n0 + r) * kH + k0 + c);
    }
}

// ============ fp32 -> f16 hi/lo split ============
__global__ __launch_bounds__(256) void split2(const float* __restrict__ X,
    _Float16* __restrict__ H, _Float16* __restrict__ L, int n)
{
    int i = (blockIdx.x * 256 + threadIdx.x) * 4;
    if (i >= n) return;
    float4 v = *(const float4*)&X[i];
    split_write(v.x, H, L, i);
    split_write(v.y, H, L, i + 1);
    split_write(v.z, H, L, i + 2);
    split_write(v.w, H, L, i + 3);
}

// ---------------- LN(residual) + optional f16 planes ----------------
__global__ __launch_bounds__(256) void ln_residual(const float* __restrict__ X,
    const float* __restrict__ A, const float* __restrict__ g,
    const float* __restrict__ lb, float* __restrict__ Y,
    _Float16* __restrict__ Yh, _Float16* __restrict__ Yl)
{
    const size_t row = blockIdx.x;
    const int tid = threadIdx.x;
    __shared__ float red[4];
    float x[3];
    float sum = 0.f;
    #pragma unroll
    for (int i = 0; i < 3; ++i) {
        int c = tid + i * 256;
        x[i] = X[row * kH + c] + A[row * kH + c];
        sum += x[i];
    }
    for (int o = 32; o > 0; o >>= 1) sum += __shfl_xor(sum, o);
    if ((tid & 63) == 0) red[tid >> 6] = sum;
    __syncthreads();
    sum = red[0] + red[1] + red[2] + red[3];
    float mean = sum * (1.0f / 768.0f);
    float vs = 0.f;
    #pragma unroll
    for (int i = 0; i < 3; ++i) { float d = x[i] - mean; vs += d * d; }
    for (int o = 32; o > 0; o >>= 1) vs += __shfl_xor(vs, o);
    __syncthreads();
    if ((tid & 63) == 0) red[tid >> 6] = vs;
    __syncthreads();
    vs = red[0] + red[1] + red[2] + red[3];
    float inv = 1.0f / sqrtf(vs * (1.0f / 768.0f) + 1e-12f);
    #pragma unroll
    for (int i = 0; i < 3; ++i) {
        int c = tid + i * 256;
        float y = (x[i] - mean) * inv * g[c] + lb[c];
        Y[row * kH + c] = y;
        if (Yh) split_write(y, Yh, Yl, row * kH + c);
    }
}

// ---------------- mean over heads of P[B,NH,NL,S] -> [B,NL,S] ----------------
__global__ __launch_bounds__(256) void mean_heads(const float* __restrict__ P,
    float* __restrict__ out)
{
    const int bq = blockIdx.x;
    const int b = bq / kNL, q = bq % kNL;
    for (int s = threadIdx.x; s < kS; s += 256) {
        float acc = 0.f;
        for (int h = 0; h < kNH; ++h)
            acc += P[((size_t)(b * kNH + h) * kNL + q) * kS + s];
        out[(size_t)bq * kS + s] = acc * (1.0f / kNH);
    }
}

// ---------------- aas accumulation ----------------
__global__ __launch_bounds__(256) void aas_acc(const float* __restrict__ P,
    float* __restrict__ aas, int init)
{
    const int b = blockIdx.x;
    for (int idx = threadIdx.x; idx < kNL * kNL; idx += 256) {
        int q = idx >> 5, k = idx & 31;
        float acc = 0.f;
        for (int h = 0; h < kNH; ++h)
            acc += P[((size_t)(b * kNH + h) * 64 + q) * 64 + 32 + k];
        size_t o = (size_t)b * kNL * kNL + idx;
        if (init) aas[o] = acc; else aas[o] += acc;
    }
}

// ---------------- imp ----------------
__global__ __launch_bounds__(256) void imp_kernel(const float* __restrict__ aas,
    const float* __restrict__ score, float* __restrict__ imp)
{
    const int b = blockIdx.x;
    __shared__ float w[kNL];
    if (threadIdx.x < kNL) {
        float acc = 0.f;
        for (int q = 0; q < kNL; ++q)
            acc += aas[((size_t)b * kNL + q) * kNL + threadIdx.x];
        w[threadIdx.x] = acc;
    }
    __syncthreads();
    for (int s = threadIdx.x; s < kS; s += 256) {
        float acc = 0.f;
        for (int k = 0; k < kNL; ++k)
            acc += w[k] * score[((size_t)b * kNL + k) * kS + s];
        imp[(size_t)b * kS + s] = acc;
    }
}

// ---------------- rank-based top-64 ----------------
__global__ __launch_bounds__(256) void topk_kernel(const float* __restrict__ imp,
    int* __restrict__ selidx, int* __restrict__ unselidx)
{
    const int b = blockIdx.x;
    const int tid = threadIdx.x;
    __shared__ unsigned long long keys[kS];
    __shared__ int wsum[4];
    for (int i = tid; i < kS; i += 256) {
        unsigned u = __float_as_uint(imp[(size_t)b * kS + i]);
        u = (u & 0x80000000u) ? ~u : (u | 0x80000000u);
        keys[i] = ((unsigned long long)u << 32) | (unsigned)(kS - 1 - i);
    }
    __syncthreads();
    unsigned long long me[4];
    int r[4] = {0, 0, 0, 0};
    #pragma unroll
    for (int j = 0; j < 4; ++j) me[j] = keys[tid * 4 + j];
    for (int t = 0; t < kS; ++t) {
        unsigned long long k = keys[t];
        #pragma unroll
        for (int j = 0; j < 4; ++j) r[j] += (k > me[j]) ? 1 : 0;
    }
    int flag[4], cnt = 0;
    #pragma unroll
    for (int j = 0; j < 4; ++j) { flag[j] = (r[j] < kTopK); cnt += flag[j]; }
    const int lane = tid & 63, w = tid >> 6;
    int incl = cnt;
    for (int o = 1; o < 64; o <<= 1) {
        int t = __shfl_up(incl, o);
        if (lane >= o) incl += t;
    }
    if (lane == 63) wsum[w] = incl;
    __syncthreads();
    int wbase = 0;
    for (int i = 0; i < w; ++i) wbase += wsum[i];
    int sbase = wbase + incl - cnt;
    int ubase = tid * 4 - sbase;
    #pragma unroll
    for (int j = 0; j < 4; ++j) {
        int i = tid * 4 + j;
        if (flag[j]) selidx[b * kTopK + sbase++] = i;
        else         unselidx[b * (kS - kTopK) + ubase++] = i;
    }
}

// ---------------- gathers (+planes) ----------------
__global__ __launch_bounds__(256) void bcast_q(const float* __restrict__ qt,
    float* __restrict__ q, _Float16* __restrict__ Qh, _Float16* __restrict__ Ql)
{
    const int bn = blockIdx.x;
    const int n = bn & (kNL - 1);
    for (int c = threadIdx.x; c < kH; c += 256) {
        float v = qt[(size_t)n * kH + c];
        q[(size_t)bn * kH + c] = v;
        split_write(v, Qh, Ql, (size_t)bn * kH + c);
    }
}

__global__ __launch_bounds__(256) void concat_lat(const float* __restrict__ qa,
    const float* __restrict__ qt, float* __restrict__ lat,
    _Float16* __restrict__ Lh, _Float16* __restrict__ Ll)
{
    const int br = blockIdx.x;
    const int b = br >> 6, r = br & 63;
    const float* src = (r < kNL) ? qa + (size_t)(b * kNL + r) * kH
                                 : qt + (size_t)(b * kNL + (r - kNL)) * kH;
    for (int c = threadIdx.x; c < kH; c += 256) {
        float v = src[c];
        lat[(size_t)br * kH + c] = v;
        split_write(v, Lh, Ll, (size_t)br * kH + c);
    }
}

__global__ __launch_bounds__(256) void gather_q(const float* __restrict__ audio,
    const int* __restrict__ selidx, float* __restrict__ qm,
    _Float16* __restrict__ Qh, _Float16* __restrict__ Ql)
{
    const int bj = blockIdx.x;
    const int b = bj >> 6;
    const int srow = selidx[bj];
    const float* src = audio + ((size_t)b * kS + srow) * kH;
    for (int c = threadIdx.x; c < kH; c += 256) {
        float v = src[c];
        qm[(size_t)bj * kH + c] = v;
        split_write(v, Qh, Ql, (size_t)bj * kH + c);
    }
}

__global__ __launch_bounds__(256) void build_kv(const float* __restrict__ audio,
    const float* __restrict__ fused, const int* __restrict__ unselidx,
    _Float16* __restrict__ Kh, _Float16* __restrict__ Kl)
{
    const int br = blockIdx.x;
    const int b = br >> 10, r = br & 1023;
    const float* src;
    if (r < kS - kTopK) src = audio + ((size_t)b * kS + unselidx[b * (kS - kTopK) + r]) * kH;
    else                src = fused + (size_t)(b * kTopK + (r - (kS - kTopK))) * kH;
    for (int c = threadIdx.x; c < kH; c += 256)
        split_write(src[c], Kh, Kl, (size_t)br * kH + c);
}

extern "C" void kernel_launch(void* const* d_in, const int* in_sizes, int n_in,
                              void* d_out, int out_size, void* d_ws, size_t ws_size,
                              hipStream_t stream)
{
    const float* audio    = (const float*)d_in[0];
    const float* text     = (const float*)d_in[1];
    const int*   amask    = (const int*)  d_in[2];
    const float* audio_qt = (const float*)d_in[3];
    const float* text_qt  = (const float*)d_in[4];
    const float* tm_w  = (const float*)d_in[5];
    const float* tm_b  = (const float*)d_in[6];
    const float* tm_g  = (const float*)d_in[7];
    const float* tm_lb = (const float*)d_in[8];
    const float* am_w  = (const float*)d_in[9];
    const float* am_b  = (const float*)d_in[10];
    const float* am_g  = (const float*)d_in[11];
    const float* am_lb = (const float*)d_in[12];
    const float* mg_w  = (const float*)d_in[13];
    const float* mg_b  = (const float*)d_in[14];
    const float* mg_g  = (const float*)d_in[15];
    const float* mg_lb = (const float*)d_in[16];
    const float* sel_w  = (const float*)d_in[17];
    const float* sel_b  = (const float*)d_in[18];
    const float* sel_g  = (const float*)d_in[19];
    const float* sel_lb = (const float*)d_in[20];
    (void)in_sizes; (void)n_in; (void)out_size;

    char* base = (char*)d_ws;
    size_t off = 0;
    auto A = [&](size_t bytes) {
        off = (off + 255) & ~(size_t)255;
        void* p = base + off; off += bytes; return p;
    };
    float* Pbuf   = (float*)A((size_t)kB * kNH * 64 * kS * 4);
    float* attA   = (float*)A((size_t)2048 * kH * 4);
    float* q_text = (float*)A((size_t)1024 * kH * 4);
    float* q_audio= (float*)A((size_t)1024 * kH * 4);
    float* latent = (float*)A((size_t)2048 * kH * 4);
    float* qmerge = (float*)A((size_t)2048 * kH * 4);
    float* latsc  = (float*)A((size_t)kB * kNL * kS * 4);
    float* aas    = (float*)A((size_t)kB * kNL * kNL * 4);
    float* impb   = (float*)A((size_t)kB * kS * 4);
    int* selidx   = (int*)A((size_t)kB * kTopK * 4);
    int* unselidx = (int*)A((size_t)kB * (kS - kTopK) * 4);
    _Float16* Wh  = (_Float16*)A(8 * kMat * 2);        // per-layer arena
    _Float16* Wl  = (_Float16*)A(8 * kMat * 2);
    _Float16* BGh = (_Float16*)A((size_t)kB * kS * kH * 2);
    _Float16* BGl = (_Float16*)A((size_t)kB * kS * kH * 2);
    _Float16* PTh = (_Float16*)A((size_t)kB * kT * kH * 2);
    _Float16* PTl = (_Float16*)A((size_t)kB * kT * kH * 2);
    _Float16* PLqh= (_Float16*)A((size_t)2048 * kH * 2);
    _Float16* PLql= (_Float16*)A((size_t)2048 * kH * 2);
    _Float16* PLoh= (_Float16*)A((size_t)2048 * kH * 2);
    _Float16* PLol= (_Float16*)A((size_t)2048 * kH * 2);
    _Float16* KVh = (_Float16*)A((size_t)kB * kS * kH * 2);
    _Float16* KVl = (_Float16*)A((size_t)kB * kS * kH * 2);
    if (off > ws_size) return;

    _Float16* Qh = PLoh;   // Q planes alias attn-out planes (disjoint lifetimes)
    _Float16* Ql = PLol;

    auto attn = [&](const float* qf, int Lq,
                    const _Float16* qah, const _Float16* qal,
                    const _Float16* eah, const _Float16* eal, int Lk,
                    int wmat, const float* bias, const float* g, const float* lb,
                    const int* mask, int capture, bool np3,
                    float* q_out, _Float16* oh, _Float16* ol)
    {
        const int Mq = kB * Lq, Mk = kB * Lk;
        const _Float16* WhB = Wh + (size_t)wmat * kMat;
        const _Float16* WlB = Wl + (size_t)wmat * kMat;
        if (Lk >= 256) {
            // Q projection: small-tile dispatch
            dim3 gq(Mq / 64, 12, 1);
            if (np3) gemm16s<3><<<gq, 256, 0, stream>>>(qah, qal, qah, qal, WhB, WlB, bias,
                         Qh, Ql, nullptr, nullptr, nullptr, nullptr, Mq, Mq);
            else     gemm16s<1><<<gq, 256, 0, stream>>>(qah, qal, qah, qal, WhB, WlB, bias,
                         Qh, Ql, nullptr, nullptr, nullptr, nullptr, Mq, Mq);
            // K projection: XCD-swizzled A-panel-major big GEMM
            const int nwgK = 6 * (Mk / 128);
            if (np3) gemm16x<3><<<nwgK, 256, 0, stream>>>(eah, eal, WhB + 1 * kMat, WlB + 1 * kMat,
                         bias + 1 * kH, KVh, KVl, Mk);
            else     gemm16x<1><<<nwgK, 256, 0, stream>>>(eah, eal, WhB + 1 * kMat, WlB + 1 * kMat,
                         bias + 1 * kH, KVh, KVl, Mk);
            dim3 g2(kB * kNH, Lq / 32);
            if (np3) attn_big<3><<<g2, 256, 0, stream>>>(Qh, Ql, KVh, KVl, Pbuf, Lq, Lk);
            else     attn_big<1><<<g2, 256, 0, stream>>>(Qh, Ql, KVh, KVl, Pbuf, Lq, Lk);
            if (capture == 1) mean_heads<<<kB * kNL, 256, 0, stream>>>(Pbuf, latsc);
            // V projection (overwrites K planes; K dead after scores)
            if (np3) gemm16x<3><<<nwgK, 256, 0, stream>>>(eah, eal, WhB + 2 * kMat, WlB + 2 * kMat,
                         bias + 2 * kH, KVh, KVl, Mk);
            else     gemm16x<1><<<nwgK, 256, 0, stream>>>(eah, eal, WhB + 2 * kMat, WlB + 2 * kMat,
                         bias + 2 * kH, KVh, KVl, Mk);
            if (Lq == 32) {
                if (np3) pv_mfma<32, 3><<<kB * kNH, 128, 0, stream>>>(Pbuf, KVh, KVl, PLoh, PLol, Lk);
                else     pv_mfma<32, 1><<<kB * kNH, 128, 0, stream>>>(Pbuf, KVh, KVl, PLoh, PLol, Lk);
            } else {
                if (np3) pv_mfma<64, 3><<<kB * kNH, 256, 0, stream>>>(Pbuf, KVh, KVl, PLoh, PLol, Lk);
                else     pv_mfma<64, 1><<<kB * kNH, 256, 0, stream>>>(Pbuf, KVh, KVl, PLoh, PLol, Lk);
            }
        } else {
            _Float16* V2h = KVh + (size_t)Mk * kH;
            _Float16* V2l = KVl + (size_t)Mk * kH;
            const int gx = (Mq > Mk ? Mq : Mk) / 64;
            dim3 g1(gx, 12, 3);
            if (np3) gemm16s<3><<<g1, 256, 0, stream>>>(qah, qal, eah, eal, WhB, WlB, bias,
                         Qh, Ql, KVh, KVl, V2h, V2l, Mq, Mk);
            else     gemm16s<1><<<g1, 256, 0, stream>>>(qah, qal, eah, eal, WhB, WlB, bias,
                         Qh, Ql, KVh, KVl, V2h, V2l, Mq, Mk);
            if (Lq == 32 && Lk == 32)
                attn_small<32, 32, 3, false, false><<<kB * kNH, 128, 0, stream>>>(
                    Qh, Ql, KVh, KVl, V2h, V2l, PLoh, PLol, nullptr, nullptr);
            else if (Lq == 32 && Lk == 64)
                attn_small<32, 64, 3, true, false><<<kB * kNH, 128, 0, stream>>>(
                    Qh, Ql, KVh, KVl, V2h, V2l, PLoh, PLol, nullptr, mask);
            else if (np3)
                attn_small<64, 64, 3, false, true><<<kB * kNH, 256, 0, stream>>>(
                    Qh, Ql, KVh, KVl, V2h, V2l, PLoh, PLol, Pbuf, nullptr);
            else
                attn_small<64, 64, 1, false, false><<<kB * kNH, 256, 0, stream>>>(
                    Qh, Ql, KVh, KVl, V2h, V2l, PLoh, PLol, nullptr, nullptr);
            if (capture == 2)      aas_acc<<<kB, 256, 0, stream>>>(Pbuf, aas, 1);
            else if (capture == 3) aas_acc<<<kB, 256, 0, stream>>>(Pbuf, aas, 0);
        }
        dim3 g4(Mq / 64, 12);
        if (np3) gemm_o32s<3><<<g4, 256, 0, stream>>>(PLoh, PLol, WhB + 3 * kMat, WlB + 3 * kMat,
                     bias + 3 * kH, attA, Mq);
        else     gemm_o32s<1><<<g4, 256, 0, stream>>>(PLoh, PLol, WhB + 3 * kMat, WlB + 3 * kMat,
                     bias + 3 * kH, attA, Mq);
        ln_residual<<<Mq, 256, 0, stream>>>(qf, attA, g, lb, q_out, oh, ol);
    };

    split2<<<(kB * kT * kH) / 1024, 256, 0, stream>>>(text, PTh, PTl, kB * kT * kH);
    split2<<<(kB * kS * kH) / 1024, 256, 0, stream>>>(audio, BGh, BGl, kB * kS * kH);

    // ---- text token merger (fp16x2; per-layer weight conversion) ----
    bcast_q<<<kB * kNL, 256, 0, stream>>>(text_qt, q_text, PLqh, PLql);
    for (int l = 0; l < kL; ++l) {
        wconv<<<dim3(24, 24, 8), 256, 0, stream>>>(tm_w + (size_t)l * 8 * kMat, Wh, Wl);
        attn(q_text, kNL, PLqh, PLql, PLqh, PLql, kNL, 0,
             tm_b + (size_t)l * 8 * kH, tm_g + (size_t)l * 2 * kH, tm_lb + (size_t)l * 2 * kH,
             nullptr, 0, true, q_text, PLqh, PLql);
        attn(q_text, kNL, PLqh, PLql, PTh, PTl, kT, 4,
             tm_b + ((size_t)l * 8 + 4) * kH, tm_g + ((size_t)l * 2 + 1) * kH, tm_lb + ((size_t)l * 2 + 1) * kH,
             amask, 0, true, q_text, PLqh, PLql);
    }
    // ---- audio token merger (capture last-layer cross probs) ----
    bcast_q<<<kB * kNL, 256, 0, stream>>>(audio_qt, q_audio, PLqh, PLql);
    for (int l = 0; l < kL; ++l) {
        wconv<<<dim3(24, 24, 8), 256, 0, stream>>>(am_w + (size_t)l * 8 * kMat, Wh, Wl);
        attn(q_audio, kNL, PLqh, PLql, PLqh, PLql, kNL, 0,
             am_b + (size_t)l * 8 * kH, am_g + (size_t)l * 2 * kH, am_lb + (size_t)l * 2 * kH,
             nullptr, 0, true, q_audio, PLqh, PLql);
        attn(q_audio, kNL, PLqh, PLql, BGh, BGl, kS, 4,
             am_b + ((size_t)l * 8 + 4) * kH, am_g + ((size_t)l * 2 + 1) * kH, am_lb + ((size_t)l * 2 + 1) * kH,
             nullptr, (l == kL - 1) ? 1 : 0, true, q_audio, PLqh, PLql);
    }
    concat_lat<<<kB * 64, 256, 0, stream>>>(q_audio, q_text, latent, PLqh, PLql);
    // ---- self block over 64 latents (captures both layers) ----
    for (int l = 0; l < kL; ++l) {
        wconv<<<dim3(24, 24, 4), 256, 0, stream>>>(sel_w + (size_t)l * 4 * kMat, Wh, Wl);
        attn(latent, 64, PLqh, PLql, PLqh, PLql, 64, 0,
             sel_b + (size_t)l * 4 * kH, sel_g + (size_t)l * kH, sel_lb + (size_t)l * kH,
             nullptr, (l == 0) ? 2 : 3, true, latent, PLqh, PLql);
    }
    // ---- selection ----
    imp_kernel<<<kB, 256, 0, stream>>>(aas, latsc, impb);
    topk_kernel<<<kB, 256, 0, stream>>>(impb, selidx, unselidx);
    gather_q<<<kB * kTopK, 256, 0, stream>>>(audio, selidx, qmerge, PLqh, PLql);
    build_kv<<<kB * kS, 256, 0, stream>>>(audio, latent, unselidx, BGh, BGl);
    // ---- merge block (fp16 1-pass) ----
    for (int l = 0; l < kL; ++l) {
        wconv<<<dim3(24, 24, 8), 256, 0, stream>>>(mg_w + (size_t)l * 8 * kMat, Wh, Wl);
        attn(qmerge, 64, PLqh, PLql, PLqh, PLql, 64, 0,
             mg_b + (size_t)l * 8 * kH, mg_g + (size_t)l * 2 * kH, mg_lb + (size_t)l * 2 * kH,
             nullptr, 0, false, qmerge, PLqh, PLql);
        float* qo = (l == kL - 1) ? (float*)d_out : qmerge;
        _Float16* oh = (l == kL - 1) ? nullptr : PLqh;
        _Float16* ol = (l == kL - 1) ? nullptr : PLql;
        attn(qmerge, 64, PLqh, PLql, BGh, BGl, kS, 4,
             mg_b + ((size_t)l * 8 + 4) * kH, mg_g + ((size_t)l * 2 + 1) * kH, mg_lb + ((size_t)l * 2 + 1) * kH,
             nullptr, 0, false, qo, oh, ol);
    }
}

// Round 11
// 2010.731 us; speedup vs baseline: 1.1304x; 1.0385x over previous
//
#include <hip/hip_runtime.h>
#include <hip/hip_bf16.h>
#include <math.h>

namespace {
constexpr int kB = 32, kS = 1024, kT = 64, kH = 768, kNH = 12, kDH = 64;
constexpr int kNL = 32, kTopK = 64, kL = 2;
constexpr size_t kMat = (size_t)kH * kH;   // 589824
}

typedef _Float16 half8 __attribute__((ext_vector_type(8)));
typedef float floatx4 __attribute__((ext_vector_type(4)));

#define AS1U(p) ((const __attribute__((address_space(1))) unsigned int*)(p))
#define AS3U(p) ((__attribute__((address_space(3))) unsigned int*)(p))

__device__ __forceinline__ void split_write(float v, _Float16* H, _Float16* L, size_t i) {
    _Float16 h = (_Float16)v;
    H[i] = h;
    L[i] = (_Float16)(v - (float)h);
}

// ============ single-matrix big GEMM (128x128), XCD-swizzled grid, 2-phase dbuf ============
// Per K-step: {barrier; issue STAGE(next) async; ds_read(cur)+MFMA}. The next
// iteration's __syncthreads (full vmcnt drain) fences staging completion AND
// read-before-overwrite. Loads fly during MFMA -> latency hidden, 1 barrier/step.
template<int NP>
__global__ __launch_bounds__(256) void gemm16x(
    const _Float16* __restrict__ Ah_, const _Float16* __restrict__ Al_,
    const _Float16* __restrict__ Bh_, const _Float16* __restrict__ Bl_,
    const float* __restrict__ bias,
    _Float16* __restrict__ Oh, _Float16* __restrict__ Ol, int M)
{
    const int nwg = gridDim.x;
    const int bid = blockIdx.x;
    const int cpx = nwg >> 3;
    const int swz = (bid & 7) * cpx + (bid >> 3);
    const int xn = swz % 6;
    const int ym = swz / 6;
    if (ym * 128 >= M) return;

    constexpr int NPL = (NP == 3) ? 4 : 2;
    __shared__ _Float16 lds[2][NPL * 4096];
    const int tid = threadIdx.x;
    const int lane = tid & 63, wave = tid >> 6;
    const size_t rm = (size_t)ym * 128;
    const size_t cn = (size_t)xn * 128;
    const int wr = (wave >> 1) * 64, wc = (wave & 1) * 64;

    const int lrow = lane >> 2;
    const int lchunk = (lane & 3) ^ ((lane >> 3) & 3);
    const int q = lane >> 4;
    const int fr = lane & 15;
    const int rslot = q ^ ((fr >> 1) & 3);     // XOR swizzle -> 2-way aliasing (free)

    const _Float16* gsrc;
    int lplane, jbase;
    if constexpr (NP == 3) {
        gsrc = (wave == 0) ? Ah_ + rm * kH : (wave == 1) ? Al_ + rm * kH
             : (wave == 2) ? Bh_ + cn * kH : Bl_ + cn * kH;
        lplane = wave;
        jbase = 0;
    } else {
        gsrc = (wave < 2) ? Ah_ + rm * kH : Bh_ + cn * kH;
        lplane = wave >> 1;
        jbase = (wave & 1) * 4;
    }
    constexpr int CPW = (NP == 3) ? 8 : 4;

    auto stage = [&](int buf, int k0) {
        #pragma unroll
        for (int c = 0; c < CPW; ++c) {
            int j = jbase + c;
            const _Float16* src = gsrc + (size_t)(j * 16 + lrow) * kH + k0 + lchunk * 8;
            _Float16* dst = &lds[buf][lplane * 4096 + j * 512 + lane * 8];
            __builtin_amdgcn_global_load_lds(AS1U(src), AS3U(dst), 16, 0, 0);
        }
    };

    floatx4 acc[4][4] = {};
    int cur = 0;
    stage(0, 0);
    constexpr int NT = kH / 32;  // 24
    for (int kt = 0; kt < NT; ++kt) {
        __syncthreads();                          // buf[cur] staged; prior reads fenced
        if (kt + 1 < NT) stage(cur ^ 1, (kt + 1) * 32);
        const _Float16* L = lds[cur];
        half8 ah[4], bh[4], al[4], bl[4];
        #pragma unroll
        for (int m = 0; m < 4; ++m) {
            int r = wr + m * 16 + fr;
            ah[m] = *(const half8*)&L[r * 32 + rslot * 8];
            if constexpr (NP == 3) al[m] = *(const half8*)&L[4096 + r * 32 + rslot * 8];
        }
        constexpr int pb = (NP == 3) ? 2 : 1;
        #pragma unroll
        for (int n = 0; n < 4; ++n) {
            int r = wc + n * 16 + fr;
            bh[n] = *(const half8*)&L[pb * 4096 + r * 32 + rslot * 8];
            if constexpr (NP == 3) bl[n] = *(const half8*)&L[3 * 4096 + r * 32 + rslot * 8];
        }
        #pragma unroll
        for (int m = 0; m < 4; ++m)
            #pragma unroll
            for (int n = 0; n < 4; ++n) {
                acc[m][n] = __builtin_amdgcn_mfma_f32_16x16x32_f16(ah[m], bh[n], acc[m][n], 0, 0, 0);
                if constexpr (NP == 3) {
                    acc[m][n] = __builtin_amdgcn_mfma_f32_16x16x32_f16(ah[m], bl[n], acc[m][n], 0, 0, 0);
                    acc[m][n] = __builtin_amdgcn_mfma_f32_16x16x32_f16(al[m], bh[n], acc[m][n], 0, 0, 0);
                }
            }
        cur ^= 1;
    }
    #pragma unroll
    for (int m = 0; m < 4; ++m) {
        int row0 = wr + m * 16 + (lane >> 4) * 4;
        #pragma unroll
        for (int n = 0; n < 4; ++n) {
            int col = (int)cn + wc + n * 16 + fr;
            float bv = bias[col];
            #pragma unroll
            for (int j = 0; j < 4; ++j) {
                float v = acc[m][n][j] + bv;
                size_t oi = (rm + row0 + j) * (size_t)kH + col;
                _Float16 hh = (_Float16)v;
                Oh[oi] = hh;
                if constexpr (NP == 3) Ol[oi] = (_Float16)(v - (float)hh);
            }
        }
    }
}

// ============ small-M fused QKV GEMM (64x64 tile), 2-phase dbuf ============
template<int NP>
__global__ __launch_bounds__(256) void gemm16s(
    const _Float16* __restrict__ Aqh, const _Float16* __restrict__ Aql,
    const _Float16* __restrict__ Aeh, const _Float16* __restrict__ Ael,
    const _Float16* __restrict__ Whb, const _Float16* __restrict__ Wlb,
    const float* __restrict__ bias,
    _Float16* __restrict__ O0h, _Float16* __restrict__ O0l,
    _Float16* __restrict__ O1h, _Float16* __restrict__ O1l,
    _Float16* __restrict__ O2h, _Float16* __restrict__ O2l,
    int Mq, int Mk)
{
    const int z = blockIdx.z;
    const int M = (z == 0) ? Mq : Mk;
    if ((int)blockIdx.x * 64 >= M) return;
    const _Float16* Ah = (z == 0) ? Aqh : Aeh;
    const _Float16* Al = (z == 0) ? Aql : Ael;
    const _Float16* Bh = Whb + (size_t)z * kMat;
    const _Float16* Bl = Wlb + (size_t)z * kMat;
    const float* bz = bias + z * kH;
    _Float16* Oh = (z == 0) ? O0h : (z == 1) ? O1h : O2h;
    _Float16* Ol = (z == 0) ? O0l : (z == 1) ? O1l : O2l;

    constexpr int NPL = (NP == 3) ? 4 : 2;
    __shared__ _Float16 lds[2][NPL * 2048];
    const int tid = threadIdx.x;
    const int lane = tid & 63, wave = tid >> 6;
    const size_t rm = (size_t)blockIdx.x * 64;
    const size_t cn = (size_t)blockIdx.y * 64;
    const int wr = (wave >> 1) * 32, wc = (wave & 1) * 32;

    const int lrow = lane >> 2;
    const int lchunk = (lane & 3) ^ ((lane >> 3) & 3);
    const int q = lane >> 4;
    const int fr = lane & 15;
    const int rslot = q ^ ((fr >> 1) & 3);

    const _Float16* gsrc;
    int lplane, jbase;
    if constexpr (NP == 3) {
        gsrc = (wave == 0) ? Ah + rm * kH : (wave == 1) ? Al + rm * kH
             : (wave == 2) ? Bh + cn * kH : Bl + cn * kH;
        lplane = wave;
        jbase = 0;
    } else {
        gsrc = (wave < 2) ? Ah + rm * kH : Bh + cn * kH;
        lplane = wave >> 1;
        jbase = (wave & 1) * 2;
    }
    constexpr int CPW = (NP == 3) ? 4 : 2;

    auto stage = [&](int buf, int k0) {
        #pragma unroll
        for (int c = 0; c < CPW; ++c) {
            int j = jbase + c;
            const _Float16* src = gsrc + (size_t)(j * 16 + lrow) * kH + k0 + lchunk * 8;
            _Float16* dst = &lds[buf][lplane * 2048 + j * 512 + lane * 8];
            __builtin_amdgcn_global_load_lds(AS1U(src), AS3U(dst), 16, 0, 0);
        }
    };

    floatx4 acc[2][2] = {};
    int cur = 0;
    stage(0, 0);
    constexpr int NT = kH / 32;
    for (int kt = 0; kt < NT; ++kt) {
        __syncthreads();
        if (kt + 1 < NT) stage(cur ^ 1, (kt + 1) * 32);
        const _Float16* L = lds[cur];
        half8 ah[2], bh[2], al[2], bl[2];
        #pragma unroll
        for (int m = 0; m < 2; ++m) {
            int r = wr + m * 16 + fr;
            ah[m] = *(const half8*)&L[r * 32 + rslot * 8];
            if constexpr (NP == 3) al[m] = *(const half8*)&L[2048 + r * 32 + rslot * 8];
        }
        constexpr int pb = (NP == 3) ? 2 : 1;
        #pragma unroll
        for (int n = 0; n < 2; ++n) {
            int r = wc + n * 16 + fr;
            bh[n] = *(const half8*)&L[pb * 2048 + r * 32 + rslot * 8];
            if constexpr (NP == 3) bl[n] = *(const half8*)&L[3 * 2048 + r * 32 + rslot * 8];
        }
        #pragma unroll
        for (int m = 0; m < 2; ++m)
            #pragma unroll
            for (int n = 0; n < 2; ++n) {
                acc[m][n] = __builtin_amdgcn_mfma_f32_16x16x32_f16(ah[m], bh[n], acc[m][n], 0, 0, 0);
                if constexpr (NP == 3) {
                    acc[m][n] = __builtin_amdgcn_mfma_f32_16x16x32_f16(ah[m], bl[n], acc[m][n], 0, 0, 0);
                    acc[m][n] = __builtin_amdgcn_mfma_f32_16x16x32_f16(al[m], bh[n], acc[m][n], 0, 0, 0);
                }
            }
        cur ^= 1;
    }
    #pragma unroll
    for (int m = 0; m < 2; ++m) {
        int row0 = wr + m * 16 + (lane >> 4) * 4;
        #pragma unroll
        for (int n = 0; n < 2; ++n) {
            int col = (int)cn + wc + n * 16 + fr;
            float bv = bz[col];
            #pragma unroll
            for (int j = 0; j < 4; ++j) {
                float v = acc[m][n][j] + bv;
                size_t oi = (rm + row0 + j) * (size_t)kH + col;
                _Float16 hh = (_Float16)v;
                Oh[oi] = hh;
                if constexpr (NP == 3) Ol[oi] = (_Float16)(v - (float)hh);
            }
        }
    }
}

// ============ O-projection GEMM (64x64 tile): fp32 out, 2-phase dbuf ============
template<int NP>
__global__ __launch_bounds__(256) void gemm_o32s(
    const _Float16* __restrict__ Ah_, const _Float16* __restrict__ Al_,
    const _Float16* __restrict__ Bh_, const _Float16* __restrict__ Bl_,
    const float* __restrict__ bias, float* __restrict__ Y, int M)
{
    constexpr int NPL = (NP == 3) ? 4 : 2;
    __shared__ _Float16 lds[2][NPL * 2048];
    const int tid = threadIdx.x;
    const int lane = tid & 63, wave = tid >> 6;
    const size_t rm = (size_t)blockIdx.x * 64;
    const size_t cn = (size_t)blockIdx.y * 64;
    const int wr = (wave >> 1) * 32, wc = (wave & 1) * 32;

    const int lrow = lane >> 2;
    const int lchunk = (lane & 3) ^ ((lane >> 3) & 3);
    const int q = lane >> 4;
    const int fr = lane & 15;
    const int rslot = q ^ ((fr >> 1) & 3);

    const _Float16* gsrc;
    int lplane, jbase;
    if constexpr (NP == 3) {
        gsrc = (wave == 0) ? Ah_ + rm * kH : (wave == 1) ? Al_ + rm * kH
             : (wave == 2) ? Bh_ + cn * kH : Bl_ + cn * kH;
        lplane = wave;
        jbase = 0;
    } else {
        gsrc = (wave < 2) ? Ah_ + rm * kH : Bh_ + cn * kH;
        lplane = wave >> 1;
        jbase = (wave & 1) * 2;
    }
    constexpr int CPW = (NP == 3) ? 4 : 2;

    auto stage = [&](int buf, int k0) {
        #pragma unroll
        for (int c = 0; c < CPW; ++c) {
            int j = jbase + c;
            const _Float16* src = gsrc + (size_t)(j * 16 + lrow) * kH + k0 + lchunk * 8;
            _Float16* dst = &lds[buf][lplane * 2048 + j * 512 + lane * 8];
            __builtin_amdgcn_global_load_lds(AS1U(src), AS3U(dst), 16, 0, 0);
        }
    };

    floatx4 acc[2][2] = {};
    int cur = 0;
    stage(0, 0);
    constexpr int NT = kH / 32;
    for (int kt = 0; kt < NT; ++kt) {
        __syncthreads();
        if (kt + 1 < NT) stage(cur ^ 1, (kt + 1) * 32);
        const _Float16* L = lds[cur];
        half8 ah[2], bh[2], al[2], bl[2];
        #pragma unroll
        for (int m = 0; m < 2; ++m) {
            int r = wr + m * 16 + fr;
            ah[m] = *(const half8*)&L[r * 32 + rslot * 8];
            if constexpr (NP == 3) al[m] = *(const half8*)&L[2048 + r * 32 + rslot * 8];
        }
        constexpr int pb = (NP == 3) ? 2 : 1;
        #pragma unroll
        for (int n = 0; n < 2; ++n) {
            int r = wc + n * 16 + fr;
            bh[n] = *(const half8*)&L[pb * 2048 + r * 32 + rslot * 8];
            if constexpr (NP == 3) bl[n] = *(const half8*)&L[3 * 2048 + r * 32 + rslot * 8];
        }
        #pragma unroll
        for (int m = 0; m < 2; ++m)
            #pragma unroll
            for (int n = 0; n < 2; ++n) {
                acc[m][n] = __builtin_amdgcn_mfma_f32_16x16x32_f16(ah[m], bh[n], acc[m][n], 0, 0, 0);
                if constexpr (NP == 3) {
                    acc[m][n] = __builtin_amdgcn_mfma_f32_16x16x32_f16(ah[m], bl[n], acc[m][n], 0, 0, 0);
                    acc[m][n] = __builtin_amdgcn_mfma_f32_16x16x32_f16(al[m], bh[n], acc[m][n], 0, 0, 0);
                }
            }
        cur ^= 1;
    }
    #pragma unroll
    for (int m = 0; m < 2; ++m) {
        int row0 = wr + m * 16 + (lane >> 4) * 4;
        #pragma unroll
        for (int n = 0; n < 2; ++n) {
            int col = (int)cn + wc + n * 16 + fr;
            float bv = bias[col];
            #pragma unroll
            for (int j = 0; j < 4; ++j)
                Y[(rm + row0 + j) * (size_t)kH + col] = acc[m][n][j] + bv;
        }
    }
}

// ============ fused scores+softmax for Lk>=256: P = softmax(QK^T/8) ============
template<int NP>
__global__ __launch_bounds__(256) void attn_big(
    const _Float16* __restrict__ Qh, const _Float16* __restrict__ Ql,
    const _Float16* __restrict__ Kh, const _Float16* __restrict__ Kl,
    float* __restrict__ P, int Lq, int Lk)
{
    constexpr int NPL = (NP == 3) ? 2 : 1;
    const int tid = threadIdx.x, lane = tid & 63, wave = tid >> 6;
    const int fr = lane & 15, part = lane >> 4;
    const int bh = blockIdx.x, b = bh / kNH, h = bh % kNH;
    const int q0 = blockIdx.y * 32;
    const int key0 = wave * 256;
    __shared__ float red[32][4];

    half8 qa[2][2][NPL];
    #pragma unroll
    for (int m = 0; m < 2; ++m)
        #pragma unroll
        for (int c = 0; c < 2; ++c) {
            size_t ro = (size_t)(b * Lq + q0 + m * 16 + fr) * kH + h * kDH + c * 32 + part * 8;
            qa[m][c][0] = *(const half8*)&Qh[ro];
            if constexpr (NP == 3) qa[m][c][1] = *(const half8*)&Ql[ro];
        }
    floatx4 acc[2][16] = {};
    #pragma unroll
    for (int n = 0; n < 16; ++n)
        #pragma unroll
        for (int c = 0; c < 2; ++c) {
            size_t ro = (size_t)(b * Lk + key0 + n * 16 + fr) * kH + h * kDH + c * 32 + part * 8;
            half8 kh8 = *(const half8*)&Kh[ro];
            half8 kl8;
            if constexpr (NP == 3) kl8 = *(const half8*)&Kl[ro];
            #pragma unroll
            for (int m = 0; m < 2; ++m) {
                acc[m][n] = __builtin_amdgcn_mfma_f32_16x16x32_f16(qa[m][c][0], kh8, acc[m][n], 0, 0, 0);
                if constexpr (NP == 3) {
                    acc[m][n] = __builtin_amdgcn_mfma_f32_16x16x32_f16(qa[m][c][0], kl8, acc[m][n], 0, 0, 0);
                    acc[m][n] = __builtin_amdgcn_mfma_f32_16x16x32_f16(qa[m][c][1], kh8, acc[m][n], 0, 0, 0);
                }
            }
        }
    #pragma unroll
    for (int m = 0; m < 2; ++m)
        #pragma unroll
        for (int n = 0; n < 16; ++n)
            #pragma unroll
            for (int j = 0; j < 4; ++j) acc[m][n][j] *= 0.125f;
    #pragma unroll
    for (int m = 0; m < 2; ++m)
        #pragma unroll
        for (int j = 0; j < 4; ++j) {
            float v = acc[m][0][j];
            #pragma unroll
            for (int n = 1; n < 16; ++n) v = fmaxf(v, acc[m][n][j]);
            #pragma unroll
            for (int o = 1; o < 16; o <<= 1) v = fmaxf(v, __shfl_xor(v, o));
            red[m * 16 + part * 4 + j][wave] = v;
        }
    __syncthreads();
    float gm[2][4];
    #pragma unroll
    for (int m = 0; m < 2; ++m)
        #pragma unroll
        for (int j = 0; j < 4; ++j) {
            int r = m * 16 + part * 4 + j;
            gm[m][j] = fmaxf(fmaxf(red[r][0], red[r][1]), fmaxf(red[r][2], red[r][3]));
        }
    __syncthreads();
    #pragma unroll
    for (int m = 0; m < 2; ++m)
        #pragma unroll
        for (int j = 0; j < 4; ++j) {
            float s = 0.f;
            #pragma unroll
            for (int n = 0; n < 16; ++n) {
                float e = expf(acc[m][n][j] - gm[m][j]);
                acc[m][n][j] = e;
                s += e;
            }
            #pragma unroll
            for (int o = 1; o < 16; o <<= 1) s += __shfl_xor(s, o);
            red[m * 16 + part * 4 + j][wave] = s;
        }
    __syncthreads();
    #pragma unroll
    for (int m = 0; m < 2; ++m)
        #pragma unroll
        for (int j = 0; j < 4; ++j) {
            int r = m * 16 + part * 4 + j;
            float inv = 1.0f / (red[r][0] + red[r][1] + red[r][2] + red[r][3]);
            size_t rowbase = ((size_t)bh * Lq + q0 + m * 16 + part * 4 + j) * Lk + key0;
            #pragma unroll
            for (int n = 0; n < 16; ++n)
                P[rowbase + n * 16 + fr] = acc[m][n][j] * inv;
        }
}

// ============ MFMA PV (big Lk): O = P.V -> f16 planes ============
template<int LQ, int NP>
__global__ __launch_bounds__((LQ / 16) * 64) void pv_mfma(
    const float* __restrict__ P,
    const _Float16* __restrict__ Vh, const _Float16* __restrict__ Vl,
    _Float16* __restrict__ Oh, _Float16* __restrict__ Ol, int Lk)
{
    constexpr int NW = LQ / 16, NT = NW * 64;
    constexpr int NPL = (NP == 3) ? 2 : 1;
    __shared__ _Float16 vT[NPL][64][72];
    const int tid = threadIdx.x, lane = tid & 63, wave = tid >> 6;
    const int fr = lane & 15, part = lane >> 4;
    const int bh = blockIdx.x, b = bh / kNH, h = bh % kNH;
    const int qbase = wave * 16;

    floatx4 acc[4] = {};
    for (int kb = 0; kb < Lk; kb += 64) {
        for (int idx = tid; idx < 64 * 8; idx += NT) {
            int r = idx >> 3, c8 = idx & 7;
            half8 v = *(const half8*)&Vh[(size_t)(b * Lk + kb + r) * kH + h * kDH + c8 * 8];
            #pragma unroll
            for (int e = 0; e < 8; ++e) vT[0][c8 * 8 + e][r] = v[e];
            if constexpr (NP == 3) {
                half8 w = *(const half8*)&Vl[(size_t)(b * Lk + kb + r) * kH + h * kDH + c8 * 8];
                #pragma unroll
                for (int e = 0; e < 8; ++e) vT[1][c8 * 8 + e][r] = w[e];
            }
        }
        __syncthreads();
        half8 pa[2][NPL];
        #pragma unroll
        for (int c = 0; c < 2; ++c) {
            const float* src = &P[((size_t)bh * LQ + qbase + fr) * Lk + kb + c * 32 + part * 8];
            float4 x = *(const float4*)src, y = *(const float4*)(src + 4);
            float vv[8] = {x.x, x.y, x.z, x.w, y.x, y.y, y.z, y.w};
            #pragma unroll
            for (int e = 0; e < 8; ++e) {
                _Float16 hh = (_Float16)vv[e];
                pa[c][0][e] = hh;
                if constexpr (NP == 3) pa[c][1][e] = (_Float16)(vv[e] - (float)hh);
            }
        }
        #pragma unroll
        for (int n = 0; n < 4; ++n)
            #pragma unroll
            for (int c = 0; c < 2; ++c) {
                half8 bh8 = *(const half8*)&vT[0][n * 16 + fr][c * 32 + part * 8];
                acc[n] = __builtin_amdgcn_mfma_f32_16x16x32_f16(pa[c][0], bh8, acc[n], 0, 0, 0);
                if constexpr (NP == 3) {
                    half8 bl8 = *(const half8*)&vT[1][n * 16 + fr][c * 32 + part * 8];
                    acc[n] = __builtin_amdgcn_mfma_f32_16x16x32_f16(pa[c][0], bl8, acc[n], 0, 0, 0);
                    acc[n] = __builtin_amdgcn_mfma_f32_16x16x32_f16(pa[c][1], bh8, acc[n], 0, 0, 0);
                }
            }
        __syncthreads();
    }
    #pragma unroll
    for (int n = 0; n < 4; ++n)
        #pragma unroll
        for (int j = 0; j < 4; ++j) {
            size_t oi = (size_t)(b * LQ + qbase + part * 4 + j) * kH + h * kDH + n * 16 + fr;
            float v = acc[n][j];
            _Float16 hh = (_Float16)v;
            Oh[oi] = hh;
            if constexpr (NP == 3) Ol[oi] = (_Float16)(v - (float)hh);
        }
}

// ============ fully-fused small attention (Lk<=64) ============
template<int LQ, int LK, int NP, bool MASKED, bool CAPTURE>
__global__ __launch_bounds__((LQ / 16) * 64) void attn_small(
    const _Float16* Qh, const _Float16* Ql,
    const _Float16* __restrict__ Kh, const _Float16* __restrict__ Kl,
    const _Float16* __restrict__ Vh, const _Float16* __restrict__ Vl,
    _Float16* Oh, _Float16* Ol,
    float* __restrict__ Pcap, const int* __restrict__ amask)
{
    constexpr int NW = LQ / 16, NT = NW * 64, NN = LK / 16, NC = LK / 32;
    constexpr int NPL = (NP == 3) ? 2 : 1;
    constexpr int PIT = LK + 8;
    __shared__ _Float16 vT[NPL][64][PIT];
    __shared__ _Float16 Pld[NW][NPL][16][PIT];
    const int tid = threadIdx.x, lane = tid & 63, wave = tid >> 6;
    const int fr = lane & 15, part = lane >> 4;
    const int bh = blockIdx.x, b = bh / kNH, h = bh % kNH;

    for (int idx = tid; idx < LK * 8; idx += NT) {
        int r = idx >> 3, c8 = idx & 7;
        half8 v = *(const half8*)&Vh[(size_t)(b * LK + r) * kH + h * kDH + c8 * 8];
        #pragma unroll
        for (int e = 0; e < 8; ++e) vT[0][c8 * 8 + e][r] = v[e];
        if constexpr (NP == 3) {
            half8 w = *(const half8*)&Vl[(size_t)(b * LK + r) * kH + h * kDH + c8 * 8];
            #pragma unroll
            for (int e = 0; e < 8; ++e) vT[1][c8 * 8 + e][r] = w[e];
        }
    }
    half8 qa[2][NPL];
    #pragma unroll
    for (int c = 0; c < 2; ++c) {
        size_t ro = (size_t)(b * LQ + wave * 16 + fr) * kH + h * kDH + c * 32 + part * 8;
        qa[c][0] = *(const half8*)&Qh[ro];
        if constexpr (NP == 3) qa[c][1] = *(const half8*)&Ql[ro];
    }
    floatx4 acc[NN] = {};
    #pragma unroll
    for (int n = 0; n < NN; ++n)
        #pragma unroll
        for (int c = 0; c < 2; ++c) {
            size_t ro = (size_t)(b * LK + n * 16 + fr) * kH + h * kDH + c * 32 + part * 8;
            half8 kh8 = *(const half8*)&Kh[ro];
            acc[n] = __builtin_amdgcn_mfma_f32_16x16x32_f16(qa[c][0], kh8, acc[n], 0, 0, 0);
            if constexpr (NP == 3) {
                half8 kl8 = *(const half8*)&Kl[ro];
                acc[n] = __builtin_amdgcn_mfma_f32_16x16x32_f16(qa[c][0], kl8, acc[n], 0, 0, 0);
                acc[n] = __builtin_amdgcn_mfma_f32_16x16x32_f16(qa[c][1], kh8, acc[n], 0, 0, 0);
            }
        }
    #pragma unroll
    for (int n = 0; n < NN; ++n) {
        float madd = 0.f;
        if constexpr (MASKED)
            madd = (1.0f - (float)amask[b * kT + n * 16 + fr]) * -1e4f;
        #pragma unroll
        for (int j = 0; j < 4; ++j) acc[n][j] = acc[n][j] * 0.125f + madd;
    }
    #pragma unroll
    for (int j = 0; j < 4; ++j) {
        float m = acc[0][j];
        #pragma unroll
        for (int n = 1; n < NN; ++n) m = fmaxf(m, acc[n][j]);
        #pragma unroll
        for (int o = 1; o < 16; o <<= 1) m = fmaxf(m, __shfl_xor(m, o));
        float s = 0.f;
        #pragma unroll
        for (int n = 0; n < NN; ++n) { float e = expf(acc[n][j] - m); acc[n][j] = e; s += e; }
        #pragma unroll
        for (int o = 1; o < 16; o <<= 1) s += __shfl_xor(s, o);
        float inv = 1.0f / s;
        #pragma unroll
        for (int n = 0; n < NN; ++n) acc[n][j] *= inv;
    }
    #pragma unroll
    for (int n = 0; n < NN; ++n)
        #pragma unroll
        for (int j = 0; j < 4; ++j) {
            float p = acc[n][j];
            if constexpr (CAPTURE)
                Pcap[((size_t)bh * LQ + wave * 16 + part * 4 + j) * LK + n * 16 + fr] = p;
            _Float16 ph = (_Float16)p;
            Pld[wave][0][part * 4 + j][n * 16 + fr] = ph;
            if constexpr (NP == 3)
                Pld[wave][1][part * 4 + j][n * 16 + fr] = (_Float16)(p - (float)ph);
        }
    __syncthreads();
    floatx4 o4[4] = {};
    #pragma unroll
    for (int n = 0; n < 4; ++n)
        #pragma unroll
        for (int c = 0; c < NC; ++c) {
            half8 ph8 = *(const half8*)&Pld[wave][0][fr][c * 32 + part * 8];
            half8 vh8 = *(const half8*)&vT[0][n * 16 + fr][c * 32 + part * 8];
            o4[n] = __builtin_amdgcn_mfma_f32_16x16x32_f16(ph8, vh8, o4[n], 0, 0, 0);
            if constexpr (NP == 3) {
                half8 pl8 = *(const half8*)&Pld[wave][1][fr][c * 32 + part * 8];
                half8 vl8 = *(const half8*)&vT[1][n * 16 + fr][c * 32 + part * 8];
                o4[n] = __builtin_amdgcn_mfma_f32_16x16x32_f16(ph8, vl8, o4[n], 0, 0, 0);
                o4[n] = __builtin_amdgcn_mfma_f32_16x16x32_f16(pl8, vh8, o4[n], 0, 0, 0);
            }
        }
    #pragma unroll
    for (int n = 0; n < 4; ++n)
        #pragma unroll
        for (int j = 0; j < 4; ++j) {
            size_t oi = (size_t)(b * LQ + wave * 16 + part * 4 + j) * kH + h * kDH + n * 16 + fr;
            float v = o4[n][j];
            _Float16 hh = (_Float16)v;
            Oh[oi] = hh;
            if constexpr (NP == 3) Ol[oi] = (_Float16)(v - (float)hh);
        }
}

// ============ weight convert: W fp32 -> transposed hi/lo f16 ============
__global__ __launch_bounds__(256) void wconv(const float* __restrict__ W,
    _Float16* __restrict__ Th, _Float16* __restrict__ Tl)
{
    __shared__ float t[32][33];
    const int mat = blockIdx.z;
    const int k0 = blockIdx.y * 32, n0 = blockIdx.x * 32;
    const int tid = threadIdx.x;
    #pragma unroll
    for (int i = 0; i < 4; ++i) {
        int e = tid + i * 256, r = e >> 5, c = e & 31;
        t[r][c] = W[(size_t)mat * kMat + (size_t)(k0 + r) * kH + n0 + c];
    }
    __syncthreads();
    #pragma unroll
    for (int i = 0; i < 4; ++i) {
        int e = tid + i * 256, r = e >> 5, c = e & 31;
        float v = t[c][r];
        split_write(v, Th, Tl, (size_t)mat * kMat + (size_t)(n0 + r) * kH + k0 + c);
    }
}

// ============ fp32 -> f16 hi/lo split ============
__global__ __launch_bounds__(256) void split2(const float* __restrict__ X,
    _Float16* __restrict__ H, _Float16* __restrict__ L, int n)
{
    int i = (blockIdx.x * 256 + threadIdx.x) * 4;
    if (i >= n) return;
    float4 v = *(const float4*)&X[i];
    split_write(v.x, H, L, i);
    split_write(v.y, H, L, i + 1);
    split_write(v.z, H, L, i + 2);
    split_write(v.w, H, L, i + 3);
}

// ---------------- LN(residual) + optional f16 planes ----------------
__global__ __launch_bounds__(256) void ln_residual(const float* __restrict__ X,
    const float* __restrict__ A, const float* __restrict__ g,
    const float* __restrict__ lb, float* __restrict__ Y,
    _Float16* __restrict__ Yh, _Float16* __restrict__ Yl)
{
    const size_t row = blockIdx.x;
    const int tid = threadIdx.x;
    __shared__ float red[4];
    float x[3];
    float sum = 0.f;
    #pragma unroll
    for (int i = 0; i < 3; ++i) {
        int c = tid + i * 256;
        x[i] = X[row * kH + c] + A[row * kH + c];
        sum += x[i];
    }
    for (int o = 32; o > 0; o >>= 1) sum += __shfl_xor(sum, o);
    if ((tid & 63) == 0) red[tid >> 6] = sum;
    __syncthreads();
    sum = red[0] + red[1] + red[2] + red[3];
    float mean = sum * (1.0f / 768.0f);
    float vs = 0.f;
    #pragma unroll
    for (int i = 0; i < 3; ++i) { float d = x[i] - mean; vs += d * d; }
    for (int o = 32; o > 0; o >>= 1) vs += __shfl_xor(vs, o);
    __syncthreads();
    if ((tid & 63) == 0) red[tid >> 6] = vs;
    __syncthreads();
    vs = red[0] + red[1] + red[2] + red[3];
    float inv = 1.0f / sqrtf(vs * (1.0f / 768.0f) + 1e-12f);
    #pragma unroll
    for (int i = 0; i < 3; ++i) {
        int c = tid + i * 256;
        float y = (x[i] - mean) * inv * g[c] + lb[c];
        Y[row * kH + c] = y;
        if (Yh) split_write(y, Yh, Yl, row * kH + c);
    }
}

// ---------------- mean over heads of P[B,NH,NL,S] -> [B,NL,S] ----------------
__global__ __launch_bounds__(256) void mean_heads(const float* __restrict__ P,
    float* __restrict__ out)
{
    const int bq = blockIdx.x;
    const int b = bq / kNL, q = bq % kNL;
    for (int s = threadIdx.x; s < kS; s += 256) {
        float acc = 0.f;
        for (int h = 0; h < kNH; ++h)
            acc += P[((size_t)(b * kNH + h) * kNL + q) * kS + s];
        out[(size_t)bq * kS + s] = acc * (1.0f / kNH);
    }
}

// ---------------- aas accumulation ----------------
__global__ __launch_bounds__(256) void aas_acc(const float* __restrict__ P,
    float* __restrict__ aas, int init)
{
    const int b = blockIdx.x;
    for (int idx = threadIdx.x; idx < kNL * kNL; idx += 256) {
        int q = idx >> 5, k = idx & 31;
        float acc = 0.f;
        for (int h = 0; h < kNH; ++h)
            acc += P[((size_t)(b * kNH + h) * 64 + q) * 64 + 32 + k];
        size_t o = (size_t)b * kNL * kNL + idx;
        if (init) aas[o] = acc; else aas[o] += acc;
    }
}

// ---------------- imp ----------------
__global__ __launch_bounds__(256) void imp_kernel(const float* __restrict__ aas,
    const float* __restrict__ score, float* __restrict__ imp)
{
    const int b = blockIdx.x;
    __shared__ float w[kNL];
    if (threadIdx.x < kNL) {
        float acc = 0.f;
        for (int q = 0; q < kNL; ++q)
            acc += aas[((size_t)b * kNL + q) * kNL + threadIdx.x];
        w[threadIdx.x] = acc;
    }
    __syncthreads();
    for (int s = threadIdx.x; s < kS; s += 256) {
        float acc = 0.f;
        for (int k = 0; k < kNL; ++k)
            acc += w[k] * score[((size_t)b * kNL + k) * kS + s];
        imp[(size_t)b * kS + s] = acc;
    }
}

// ---------------- rank-based top-64 ----------------
__global__ __launch_bounds__(256) void topk_kernel(const float* __restrict__ imp,
    int* __restrict__ selidx, int* __restrict__ unselidx)
{
    const int b = blockIdx.x;
    const int tid = threadIdx.x;
    __shared__ unsigned long long keys[kS];
    __shared__ int wsum[4];
    for (int i = tid; i < kS; i += 256) {
        unsigned u = __float_as_uint(imp[(size_t)b * kS + i]);
        u = (u & 0x80000000u) ? ~u : (u | 0x80000000u);
        keys[i] = ((unsigned long long)u << 32) | (unsigned)(kS - 1 - i);
    }
    __syncthreads();
    unsigned long long me[4];
    int r[4] = {0, 0, 0, 0};
    #pragma unroll
    for (int j = 0; j < 4; ++j) me[j] = keys[tid * 4 + j];
    for (int t = 0; t < kS; ++t) {
        unsigned long long k = keys[t];
        #pragma unroll
        for (int j = 0; j < 4; ++j) r[j] += (k > me[j]) ? 1 : 0;
    }
    int flag[4], cnt = 0;
    #pragma unroll
    for (int j = 0; j < 4; ++j) { flag[j] = (r[j] < kTopK); cnt += flag[j]; }
    const int lane = tid & 63, w = tid >> 6;
    int incl = cnt;
    for (int o = 1; o < 64; o <<= 1) {
        int t = __shfl_up(incl, o);
        if (lane >= o) incl += t;
    }
    if (lane == 63) wsum[w] = incl;
    __syncthreads();
    int wbase = 0;
    for (int i = 0; i < w; ++i) wbase += wsum[i];
    int sbase = wbase + incl - cnt;
    int ubase = tid * 4 - sbase;
    #pragma unroll
    for (int j = 0; j < 4; ++j) {
        int i = tid * 4 + j;
        if (flag[j]) selidx[b * kTopK + sbase++] = i;
        else         unselidx[b * (kS - kTopK) + ubase++] = i;
    }
}

// ---------------- gathers (+planes) ----------------
__global__ __launch_bounds__(256) void bcast_q(const float* __restrict__ qt,
    float* __restrict__ q, _Float16* __restrict__ Qh, _Float16* __restrict__ Ql)
{
    const int bn = blockIdx.x;
    const int n = bn & (kNL - 1);
    for (int c = threadIdx.x; c < kH; c += 256) {
        float v = qt[(size_t)n * kH + c];
        q[(size_t)bn * kH + c] = v;
        split_write(v, Qh, Ql, (size_t)bn * kH + c);
    }
}

__global__ __launch_bounds__(256) void concat_lat(const float* __restrict__ qa,
    const float* __restrict__ qt, float* __restrict__ lat,
    _Float16* __restrict__ Lh, _Float16* __restrict__ Ll)
{
    const int br = blockIdx.x;
    const int b = br >> 6, r = br & 63;
    const float* src = (r < kNL) ? qa + (size_t)(b * kNL + r) * kH
                                 : qt + (size_t)(b * kNL + (r - kNL)) * kH;
    for (int c = threadIdx.x; c < kH; c += 256) {
        float v = src[c];
        lat[(size_t)br * kH + c] = v;
        split_write(v, Lh, Ll, (size_t)br * kH + c);
    }
}

__global__ __launch_bounds__(256) void gather_q(const float* __restrict__ audio,
    const int* __restrict__ selidx, float* __restrict__ qm,
    _Float16* __restrict__ Qh, _Float16* __restrict__ Ql)
{
    const int bj = blockIdx.x;
    const int b = bj >> 6;
    const int srow = selidx[bj];
    const float* src = audio + ((size_t)b * kS + srow) * kH;
    for (int c = threadIdx.x; c < kH; c += 256) {
        float v = src[c];
        qm[(size_t)bj * kH + c] = v;
        split_write(v, Qh, Ql, (size_t)bj * kH + c);
    }
}

__global__ __launch_bounds__(256) void build_kv(const float* __restrict__ audio,
    const float* __restrict__ fused, const int* __restrict__ unselidx,
    _Float16* __restrict__ Kh, _Float16* __restrict__ Kl)
{
    const int br = blockIdx.x;
    const int b = br >> 10, r = br & 1023;
    const float* src;
    if (r < kS - kTopK) src = audio + ((size_t)b * kS + unselidx[b * (kS - kTopK) + r]) * kH;
    else                src = fused + (size_t)(b * kTopK + (r - (kS - kTopK))) * kH;
    for (int c = threadIdx.x; c < kH; c += 256)
        split_write(src[c], Kh, Kl, (size_t)br * kH + c);
}

extern "C" void kernel_launch(void* const* d_in, const int* in_sizes, int n_in,
                              void* d_out, int out_size, void* d_ws, size_t ws_size,
                              hipStream_t stream)
{
    const float* audio    = (const float*)d_in[0];
    const float* text     = (const float*)d_in[1];
    const int*   amask    = (const int*)  d_in[2];
    const float* audio_qt = (const float*)d_in[3];
    const float* text_qt  = (const float*)d_in[4];
    const float* tm_w  = (const float*)d_in[5];
    const float* tm_b  = (const float*)d_in[6];
    const float* tm_g  = (const float*)d_in[7];
    const float* tm_lb = (const float*)d_in[8];
    const float* am_w  = (const float*)d_in[9];
    const float* am_b  = (const float*)d_in[10];
    const float* am_g  = (const float*)d_in[11];
    const float* am_lb = (const float*)d_in[12];
    const float* mg_w  = (const float*)d_in[13];
    const float* mg_b  = (const float*)d_in[14];
    const float* mg_g  = (const float*)d_in[15];
    const float* mg_lb = (const float*)d_in[16];
    const float* sel_w  = (const float*)d_in[17];
    const float* sel_b  = (const float*)d_in[18];
    const float* sel_g  = (const float*)d_in[19];
    const float* sel_lb = (const float*)d_in[20];
    (void)in_sizes; (void)n_in; (void)out_size;

    char* base = (char*)d_ws;
    size_t off = 0;
    auto A = [&](size_t bytes) {
        off = (off + 255) & ~(size_t)255;
        void* p = base + off; off += bytes; return p;
    };
    float* Pbuf   = (float*)A((size_t)kB * kNH * 64 * kS * 4);
    float* attA   = (float*)A((size_t)2048 * kH * 4);
    float* q_text = (float*)A((size_t)1024 * kH * 4);
    float* q_audio= (float*)A((size_t)1024 * kH * 4);
    float* latent = (float*)A((size_t)2048 * kH * 4);
    float* qmerge = (float*)A((size_t)2048 * kH * 4);
    float* latsc  = (float*)A((size_t)kB * kNL * kS * 4);
    float* aas    = (float*)A((size_t)kB * kNL * kNL * 4);
    float* impb   = (float*)A((size_t)kB * kS * 4);
    int* selidx   = (int*)A((size_t)kB * kTopK * 4);
    int* unselidx = (int*)A((size_t)kB * (kS - kTopK) * 4);
    _Float16* Wh  = (_Float16*)A(8 * kMat * 2);        // per-layer arena
    _Float16* Wl  = (_Float16*)A(8 * kMat * 2);
    _Float16* BGh = (_Float16*)A((size_t)kB * kS * kH * 2);
    _Float16* BGl = (_Float16*)A((size_t)kB * kS * kH * 2);
    _Float16* PTh = (_Float16*)A((size_t)kB * kT * kH * 2);
    _Float16* PTl = (_Float16*)A((size_t)kB * kT * kH * 2);
    _Float16* PLqh= (_Float16*)A((size_t)2048 * kH * 2);
    _Float16* PLql= (_Float16*)A((size_t)2048 * kH * 2);
    _Float16* PLoh= (_Float16*)A((size_t)2048 * kH * 2);
    _Float16* PLol= (_Float16*)A((size_t)2048 * kH * 2);
    _Float16* KVh = (_Float16*)A((size_t)kB * kS * kH * 2);
    _Float16* KVl = (_Float16*)A((size_t)kB * kS * kH * 2);
    if (off > ws_size) return;

    _Float16* Qh = PLoh;   // Q planes alias attn-out planes (disjoint lifetimes)
    _Float16* Ql = PLol;

    auto attn = [&](const float* qf, int Lq,
                    const _Float16* qah, const _Float16* qal,
                    const _Float16* eah, const _Float16* eal, int Lk,
                    int wmat, const float* bias, const float* g, const float* lb,
                    const int* mask, int capture, bool np3,
                    float* q_out, _Float16* oh, _Float16* ol)
    {
        const int Mq = kB * Lq, Mk = kB * Lk;
        const _Float16* WhB = Wh + (size_t)wmat * kMat;
        const _Float16* WlB = Wl + (size_t)wmat * kMat;
        if (Lk >= 256) {
            dim3 gq(Mq / 64, 12, 1);
            if (np3) gemm16s<3><<<gq, 256, 0, stream>>>(qah, qal, qah, qal, WhB, WlB, bias,
                         Qh, Ql, nullptr, nullptr, nullptr, nullptr, Mq, Mq);
            else     gemm16s<1><<<gq, 256, 0, stream>>>(qah, qal, qah, qal, WhB, WlB, bias,
                         Qh, Ql, nullptr, nullptr, nullptr, nullptr, Mq, Mq);
            const int nwgK = 6 * (Mk / 128);
            if (np3) gemm16x<3><<<nwgK, 256, 0, stream>>>(eah, eal, WhB + 1 * kMat, WlB + 1 * kMat,
                         bias + 1 * kH, KVh, KVl, Mk);
            else     gemm16x<1><<<nwgK, 256, 0, stream>>>(eah, eal, WhB + 1 * kMat, WlB + 1 * kMat,
                         bias + 1 * kH, KVh, KVl, Mk);
            dim3 g2(kB * kNH, Lq / 32);
            if (np3) attn_big<3><<<g2, 256, 0, stream>>>(Qh, Ql, KVh, KVl, Pbuf, Lq, Lk);
            else     attn_big<1><<<g2, 256, 0, stream>>>(Qh, Ql, KVh, KVl, Pbuf, Lq, Lk);
            if (capture == 1) mean_heads<<<kB * kNL, 256, 0, stream>>>(Pbuf, latsc);
            if (np3) gemm16x<3><<<nwgK, 256, 0, stream>>>(eah, eal, WhB + 2 * kMat, WlB + 2 * kMat,
                         bias + 2 * kH, KVh, KVl, Mk);
            else     gemm16x<1><<<nwgK, 256, 0, stream>>>(eah, eal, WhB + 2 * kMat, WlB + 2 * kMat,
                         bias + 2 * kH, KVh, KVl, Mk);
            if (Lq == 32) {
                if (np3) pv_mfma<32, 3><<<kB * kNH, 128, 0, stream>>>(Pbuf, KVh, KVl, PLoh, PLol, Lk);
                else     pv_mfma<32, 1><<<kB * kNH, 128, 0, stream>>>(Pbuf, KVh, KVl, PLoh, PLol, Lk);
            } else {
                if (np3) pv_mfma<64, 3><<<kB * kNH, 256, 0, stream>>>(Pbuf, KVh, KVl, PLoh, PLol, Lk);
                else     pv_mfma<64, 1><<<kB * kNH, 256, 0, stream>>>(Pbuf, KVh, KVl, PLoh, PLol, Lk);
            }
        } else {
            _Float16* V2h = KVh + (size_t)Mk * kH;
            _Float16* V2l = KVl + (size_t)Mk * kH;
            const int gx = (Mq > Mk ? Mq : Mk) / 64;
            dim3 g1(gx, 12, 3);
            if (np3) gemm16s<3><<<g1, 256, 0, stream>>>(qah, qal, eah, eal, WhB, WlB, bias,
                         Qh, Ql, KVh, KVl, V2h, V2l, Mq, Mk);
            else     gemm16s<1><<<g1, 256, 0, stream>>>(qah, qal, eah, eal, WhB, WlB, bias,
                         Qh, Ql, KVh, KVl, V2h, V2l, Mq, Mk);
            if (Lq == 32 && Lk == 32)
                attn_small<32, 32, 3, false, false><<<kB * kNH, 128, 0, stream>>>(
                    Qh, Ql, KVh, KVl, V2h, V2l, PLoh, PLol, nullptr, nullptr);
            else if (Lq == 32 && Lk == 64)
                attn_small<32, 64, 3, true, false><<<kB * kNH, 128, 0, stream>>>(
                    Qh, Ql, KVh, KVl, V2h, V2l, PLoh, PLol, nullptr, mask);
            else if (np3)
                attn_small<64, 64, 3, false, true><<<kB * kNH, 256, 0, stream>>>(
                    Qh, Ql, KVh, KVl, V2h, V2l, PLoh, PLol, Pbuf, nullptr);
            else
                attn_small<64, 64, 1, false, false><<<kB * kNH, 256, 0, stream>>>(
                    Qh, Ql, KVh, KVl, V2h, V2l, PLoh, PLol, nullptr, nullptr);
            if (capture == 2)      aas_acc<<<kB, 256, 0, stream>>>(Pbuf, aas, 1);
            else if (capture == 3) aas_acc<<<kB, 256, 0, stream>>>(Pbuf, aas, 0);
        }
        dim3 g4(Mq / 64, 12);
        if (np3) gemm_o32s<3><<<g4, 256, 0, stream>>>(PLoh, PLol, WhB + 3 * kMat, WlB + 3 * kMat,
                     bias + 3 * kH, attA, Mq);
        else     gemm_o32s<1><<<g4, 256, 0, stream>>>(PLoh, PLol, WhB + 3 * kMat, WlB + 3 * kMat,
                     bias + 3 * kH, attA, Mq);
        ln_residual<<<Mq, 256, 0, stream>>>(qf, attA, g, lb, q_out, oh, ol);
    };

    split2<<<(kB * kT * kH) / 1024, 256, 0, stream>>>(text, PTh, PTl, kB * kT * kH);
    split2<<<(kB * kS * kH) / 1024, 256, 0, stream>>>(audio, BGh, BGl, kB * kS * kH);

    // ---- text token merger (fp16x2; per-layer weight conversion) ----
    bcast_q<<<kB * kNL, 256, 0, stream>>>(text_qt, q_text, PLqh, PLql);
    for (int l = 0; l < kL; ++l) {
        wconv<<<dim3(24, 24, 8), 256, 0, stream>>>(tm_w + (size_t)l * 8 * kMat, Wh, Wl);
        attn(q_text, kNL, PLqh, PLql, PLqh, PLql, kNL, 0,
             tm_b + (size_t)l * 8 * kH, tm_g + (size_t)l * 2 * kH, tm_lb + (size_t)l * 2 * kH,
             nullptr, 0, true, q_text, PLqh, PLql);
        attn(q_text, kNL, PLqh, PLql, PTh, PTl, kT, 4,
             tm_b + ((size_t)l * 8 + 4) * kH, tm_g + ((size_t)l * 2 + 1) * kH, tm_lb + ((size_t)l * 2 + 1) * kH,
             amask, 0, true, q_text, PLqh, PLql);
    }
    // ---- audio token merger (capture last-layer cross probs) ----
    bcast_q<<<kB * kNL, 256, 0, stream>>>(audio_qt, q_audio, PLqh, PLql);
    for (int l = 0; l < kL; ++l) {
        wconv<<<dim3(24, 24, 8), 256, 0, stream>>>(am_w + (size_t)l * 8 * kMat, Wh, Wl);
        attn(q_audio, kNL, PLqh, PLql, PLqh, PLql, kNL, 0,
             am_b + (size_t)l * 8 * kH, am_g + (size_t)l * 2 * kH, am_lb + (size_t)l * 2 * kH,
             nullptr, 0, true, q_audio, PLqh, PLql);
        attn(q_audio, kNL, PLqh, PLql, BGh, BGl, kS, 4,
             am_b + ((size_t)l * 8 + 4) * kH, am_g + ((size_t)l * 2 + 1) * kH, am_lb + ((size_t)l * 2 + 1) * kH,
             nullptr, (l == kL - 1) ? 1 : 0, true, q_audio, PLqh, PLql);
    }
    concat_lat<<<kB * 64, 256, 0, stream>>>(q_audio, q_text, latent, PLqh, PLql);
    // ---- self block over 64 latents (captures both layers) ----
    for (int l = 0; l < kL; ++l) {
        wconv<<<dim3(24, 24, 4), 256, 0, stream>>>(sel_w + (size_t)l * 4 * kMat, Wh, Wl);
        attn(latent, 64, PLqh, PLql, PLqh, PLql, 64, 0,
             sel_b + (size_t)l * 4 * kH, sel_g + (size_t)l * kH, sel_lb + (size_t)l * kH,
             nullptr, (l == 0) ? 2 : 3, true, latent, PLqh, PLql);
    }
    // ---- selection ----
    imp_kernel<<<kB, 256, 0, stream>>>(aas, latsc, impb);
    topk_kernel<<<kB, 256, 0, stream>>>(impb, selidx, unselidx);
    gather_q<<<kB * kTopK, 256, 0, stream>>>(audio, selidx, qmerge, PLqh, PLql);
    build_kv<<<kB * kS, 256, 0, stream>>>(audio, latent, unselidx, BGh, BGl);
    // ---- merge block (fp16 1-pass) ----
    for (int l = 0; l < kL; ++l) {
        wconv<<<dim3(24, 24, 8), 256, 0, stream>>>(mg_w + (size_t)l * 8 * kMat, Wh, Wl);
        attn(qmerge, 64, PLqh, PLql, PLqh, PLql, 64, 0,
             mg_b + (size_t)l * 8 * kH, mg_g + (size_t)l * 2 * kH, mg_lb + (size_t)l * 2 * kH,
             nullptr, 0, false, qmerge, PLqh, PLql);
        float* qo = (l == kL - 1) ? (float*)d_out : qmerge;
        _Float16* oh = (l == kL - 1) ? nullptr : PLqh;
        _Float16* ol = (l == kL - 1) ? nullptr : PLql;
        attn(qmerge, 64, PLqh, PLql, BGh, BGl, kS, 4,
             mg_b + ((size_t)l * 8 + 4) * kH, mg_g + ((size_t)l * 2 + 1) * kH, mg_lb + ((size_t)l * 2 + 1) * kH,
             nullptr, 0, false, qo, oh, ol);
    }
}